// Round 1
// baseline (12509.921 us; speedup 1.0000x reference)
//
#include <hip/hip_runtime.h>
#include <cstdio>
#include <cstdint>

#define S8     8
#define TENC   12
#define HDIM   256
#define FDIM   316
#define BATCH  1024
#define LDEC   48
#define G4H    1024
#define BT     16
#define SCALE_ATTN 0.0625f   // 1/sqrt(256)

__device__ __forceinline__ float sigf(float x) { return 1.0f / (1.0f + expf(-x)); }

// ---------------- transpose: in [S][R][C] -> out [S][C][R] ----------------
__global__ __launch_bounds__(256) void transpose_k(const float* __restrict__ in,
                                                   float* __restrict__ out,
                                                   int R, int C) {
  __shared__ float tile[32][33];
  const int s = blockIdx.z;
  const size_t base = (size_t)s * R * C;
  const int r0 = blockIdx.y * 32, c0 = blockIdx.x * 32;
  const int tx = threadIdx.x & 31, ty = threadIdx.x >> 5;
  for (int i = ty; i < 32; i += 8) {
    int r = r0 + i, c = c0 + tx;
    if (r < R && c < C) tile[i][tx] = in[base + (size_t)r * C + c];
  }
  __syncthreads();
  for (int i = ty; i < 32; i += 8) {
    int c = c0 + i, r = r0 + tx;
    if (c < C && r < R) out[base + (size_t)c * R + r] = tile[tx][i];
  }
}

// ---- fold GEMM: out[s][r][col] = sum_e A[s][e][r] * B[s][e][col], 256x256, K=256 ----
__global__ __launch_bounds__(256) void fold_gemm(const float* __restrict__ A, size_t sA,
                                                 const float* __restrict__ Bm, size_t sB,
                                                 float* __restrict__ out, size_t sO) {
  const int s = blockIdx.y, r0 = blockIdx.x * 32, col = threadIdx.x;
  A += (size_t)s * sA; Bm += (size_t)s * sB; out += (size_t)s * sO;
  float acc[32] = {};
  for (int e = 0; e < HDIM; ++e) {
    const float bvv = Bm[(size_t)e * HDIM + col];
#pragma unroll
    for (int r = 0; r < 32; ++r) acc[r] = fmaf(A[(size_t)e * HDIM + r0 + r], bvv, acc[r]);
  }
  for (int r = 0; r < 32; ++r) out[(size_t)(r0 + r) * HDIM + col] = acc[r];
}

// ---- fold vectors: kbv[s][h2] = Wk^T bq ; cbias[s][o] = W_out bv + b_out ----
__global__ __launch_bounds__(256) void fold_vec(const float* __restrict__ W_in_attn,
                                                const float* __restrict__ b_in_attn,
                                                const float* __restrict__ WoT,
                                                const float* __restrict__ b_out_attn,
                                                float* __restrict__ kbv,
                                                float* __restrict__ cbias) {
  const int s = blockIdx.x, t = threadIdx.x;
  const float* Wk = W_in_attn + (size_t)s * 768 * 256 + 256 * 256;
  const float* bq = b_in_attn + (size_t)s * 768;
  const float* bv = b_in_attn + (size_t)s * 768 + 512;
  const float* Wo = WoT + (size_t)s * 256 * 256;
  float a0 = 0.f, a1 = 0.f;
  for (int e = 0; e < 256; ++e) {
    a0 = fmaf(Wk[(size_t)e * 256 + t], bq[e], a0);
    a1 = fmaf(Wo[(size_t)e * 256 + t], bv[e], a1);
  }
  kbv[s * 256 + t] = a0;
  cbias[s * 256 + t] = a1 + b_out_attn[s * 256 + t];
}

// ---- decoder teacher-forced inputs: dec_in[0][b]=x[b,95,0]; dec_in[l][b]=tgt[b][l-1] ----
__global__ void build_decin(const float* __restrict__ x, const float* __restrict__ tgt,
                            float* __restrict__ dec_in) {
  int idx = blockIdx.x * 256 + threadIdx.x;
  if (idx >= LDEC * BATCH) return;
  int l = idx >> 10, b = idx & 1023;
  dec_in[idx] = (l == 0) ? x[(size_t)b * 96 * FDIM + 95 * FDIM]
                         : tgt[(size_t)b * LDEC + (l - 1)];
}

// ---------------- encoder step (one timestep, all streams) ----------------
// gates = x_t @ W_ih^T + h @ W_hh^T + biases ; LSTM update ; kp=M_k h ; vp=M_v h ; kb=kbv.h
__global__ __launch_bounds__(256) void enc_step(
    const float* __restrict__ x,
    const float* __restrict__ WtX,    // [S][316][1024]
    const float* __restrict__ WtH,    // [S][256][1024]
    const float* __restrict__ bihe, const float* __restrict__ bhhe,  // [S][1024]
    const float* __restrict__ MkT,    // [S][256][256]
    const float* __restrict__ MvT,    // [S][256][256]
    const float* __restrict__ kbv,    // [S][256]
    float* __restrict__ h, float* __restrict__ c,          // [S][B][256]
    float* __restrict__ kp, float* __restrict__ vp,        // [T][S][B][256]
    float* __restrict__ kb,                                // [T][S][B]
    int t) {
  __shared__ float xs[BT][320];   // 316 padded to 320 (float4-aligned rows)
  __shared__ float hs[BT][256];
  __shared__ float red[16][16];
  const int s = blockIdx.y, b0 = blockIdx.x * BT;
  const int tid = threadIdx.x;

  {
    const float* xb = x + (size_t)(s * TENC + t) * FDIM;
    for (int i = tid; i < BT * FDIM; i += 256) {
      int bb = i / FDIM, f = i - bb * FDIM;
      xs[bb][f] = xb[(size_t)(b0 + bb) * (96 * FDIM) + f];
    }
    const float* hb = h + ((size_t)s * BATCH + b0) * HDIM;
    for (int i = tid; i < BT * HDIM; i += 256) hs[i >> 8][i & 255] = hb[i];
  }
  __syncthreads();

  const int tg = tid & 63, tb = tid >> 6;   // 64 g-threads x 4 b-threads
  float P[4][4];
  float* hw = h + ((size_t)s * BATCH + b0) * HDIM;
  float* cw = c + ((size_t)s * BATCH + b0) * HDIM;
  const int order[4] = {0, 2, 1, 3};        // process gates i, g, f, o
#pragma unroll 1
  for (int cc = 0; cc < 4; ++cc) {
    const int chunk = order[cc];
    const int g0 = chunk * HDIM + tg * 4;
    float acc[4][4] = {};
    // x part, K=316
    {
      const float* wx = WtX + (size_t)s * FDIM * G4H + g0;
      for (int k = 0; k < FDIM; k += 4) {
        float4 xv[4];
#pragma unroll
        for (int bi = 0; bi < 4; ++bi) xv[bi] = *(const float4*)(&xs[tb * 4 + bi][k]);
        const float* w0 = wx + (size_t)k * G4H;
#pragma unroll
        for (int kk = 0; kk < 4; ++kk) {
          const float4 w = *(const float4*)(w0 + (size_t)kk * G4H);
#pragma unroll
          for (int bi = 0; bi < 4; ++bi) {
            const float xk = ((const float*)&xv[bi])[kk];
            acc[bi][0] = fmaf(xk, w.x, acc[bi][0]);
            acc[bi][1] = fmaf(xk, w.y, acc[bi][1]);
            acc[bi][2] = fmaf(xk, w.z, acc[bi][2]);
            acc[bi][3] = fmaf(xk, w.w, acc[bi][3]);
          }
        }
      }
    }
    // h part, K=256
    {
      const float* wh = WtH + (size_t)s * HDIM * G4H + g0;
      for (int k = 0; k < HDIM; k += 4) {
        float4 xv[4];
#pragma unroll
        for (int bi = 0; bi < 4; ++bi) xv[bi] = *(const float4*)(&hs[tb * 4 + bi][k]);
        const float* w0 = wh + (size_t)k * G4H;
#pragma unroll
        for (int kk = 0; kk < 4; ++kk) {
          const float4 w = *(const float4*)(w0 + (size_t)kk * G4H);
#pragma unroll
          for (int bi = 0; bi < 4; ++bi) {
            const float xk = ((const float*)&xv[bi])[kk];
            acc[bi][0] = fmaf(xk, w.x, acc[bi][0]);
            acc[bi][1] = fmaf(xk, w.y, acc[bi][1]);
            acc[bi][2] = fmaf(xk, w.z, acc[bi][2]);
            acc[bi][3] = fmaf(xk, w.w, acc[bi][3]);
          }
        }
      }
    }
    // bias + pointwise (staged per gate: i, g, f, o)
#pragma unroll
    for (int bi = 0; bi < 4; ++bi) {
      const int bb = tb * 4 + bi;
#pragma unroll
      for (int gj = 0; gj < 4; ++gj) {
        const int gidx = g0 + gj;
        const int j = gidx - chunk * HDIM;
        float gate = acc[bi][gj] + bihe[s * G4H + gidx] + bhhe[s * G4H + gidx];
        if (cc == 0) {                    // i
          P[bi][gj] = sigf(gate);
        } else if (cc == 1) {             // g
          P[bi][gj] *= tanhf(gate);
        } else if (cc == 2) {             // f
          float cn = fmaf(sigf(gate), cw[(size_t)bb * HDIM + j], P[bi][gj]);
          cw[(size_t)bb * HDIM + j] = cn;
          P[bi][gj] = tanhf(cn);
        } else {                          // o
          float hn = sigf(gate) * P[bi][gj];
          hw[(size_t)bb * HDIM + j] = hn;
          P[bi][gj] = hn;
        }
      }
    }
  }
  __syncthreads();                        // all reads of old hs done
#pragma unroll
  for (int bi = 0; bi < 4; ++bi)
#pragma unroll
    for (int gj = 0; gj < 4; ++gj) hs[tb * 4 + bi][tg * 4 + gj] = P[bi][gj];
  __syncthreads();

  // kp / vp projections: [BT][256] = hs @ MkT / MvT
  {
    const int c0 = tg * 4;
    float a1[4][4] = {}, a2[4][4] = {};
    const float* mk = MkT + (size_t)s * HDIM * HDIM + c0;
    const float* mv = MvT + (size_t)s * HDIM * HDIM + c0;
    for (int k = 0; k < HDIM; k += 4) {
      float4 xv[4];
#pragma unroll
      for (int bi = 0; bi < 4; ++bi) xv[bi] = *(const float4*)(&hs[tb * 4 + bi][k]);
#pragma unroll
      for (int kk = 0; kk < 4; ++kk) {
        const float4 wk4 = *(const float4*)(mk + (size_t)(k + kk) * HDIM);
        const float4 wv4 = *(const float4*)(mv + (size_t)(k + kk) * HDIM);
#pragma unroll
        for (int bi = 0; bi < 4; ++bi) {
          const float hv = ((const float*)&xv[bi])[kk];
          a1[bi][0] = fmaf(hv, wk4.x, a1[bi][0]);
          a1[bi][1] = fmaf(hv, wk4.y, a1[bi][1]);
          a1[bi][2] = fmaf(hv, wk4.z, a1[bi][2]);
          a1[bi][3] = fmaf(hv, wk4.w, a1[bi][3]);
          a2[bi][0] = fmaf(hv, wv4.x, a2[bi][0]);
          a2[bi][1] = fmaf(hv, wv4.y, a2[bi][1]);
          a2[bi][2] = fmaf(hv, wv4.z, a2[bi][2]);
          a2[bi][3] = fmaf(hv, wv4.w, a2[bi][3]);
        }
      }
    }
    float* kpw = kp + (((size_t)t * S8 + s) * BATCH + b0) * HDIM;
    float* vpw = vp + (((size_t)t * S8 + s) * BATCH + b0) * HDIM;
#pragma unroll
    for (int bi = 0; bi < 4; ++bi) {
      const int bb = tb * 4 + bi;
      *(float4*)(&kpw[(size_t)bb * HDIM + c0]) = make_float4(a1[bi][0], a1[bi][1], a1[bi][2], a1[bi][3]);
      *(float4*)(&vpw[(size_t)bb * HDIM + c0]) = make_float4(a2[bi][0], a2[bi][1], a2[bi][2], a2[bi][3]);
    }
  }
  // kb = kbv . h_new  (per b)
  {
    const int bb = tid >> 4, p = tid & 15;
    float a = 0.f;
    const float* kv = kbv + s * HDIM;
    for (int k = p * 16; k < p * 16 + 16; ++k) a = fmaf(kv[k], hs[bb][k], a);
    red[bb][p] = a;
  }
  __syncthreads();
  if (tid < BT) {
    float a = 0.f;
#pragma unroll
    for (int p = 0; p < 16; ++p) a += red[tid][p];
    kb[((size_t)t * S8 + s) * BATCH + b0 + tid] = a;
  }
}

// ---------------- decoder step (fully fused) ----------------
__global__ __launch_bounds__(256) void dec_step(
    const float* __restrict__ WtHd,   // [S][256][1024]
    const float* __restrict__ Wihd,   // [S][1024]  (W_ih_d[:,:,0])
    const float* __restrict__ bihd, const float* __restrict__ bhhd,  // [S][1024]
    const float* __restrict__ kp, const float* __restrict__ vp,      // [T][S][B][256]
    const float* __restrict__ kb,                                    // [T][S][B]
    const float* __restrict__ cbias,  // [S][256]
    const float* __restrict__ Wfo,    // [S][512]
    const float* __restrict__ bfo,    // [S]
    const float* __restrict__ decin,  // [L][B]
    float* __restrict__ h, float* __restrict__ c,
    float* __restrict__ douts,        // [L][S][B]
    int l) {
  __shared__ float hs[BT][256];
  __shared__ float hn[BT][256];
  __shared__ float sc[BT][12];
  __shared__ float red[16][16];
  const int s = blockIdx.y, b0 = blockIdx.x * BT;
  const int tid = threadIdx.x;
  {
    const float* hb = h + ((size_t)s * BATCH + b0) * HDIM;
    for (int i = tid; i < BT * HDIM; i += 256) hs[i >> 8][i & 255] = hb[i];
  }
  __syncthreads();

  const int tg = tid & 63, tb = tid >> 6;
  float it[4];
#pragma unroll
  for (int bi = 0; bi < 4; ++bi) it[bi] = decin[(size_t)l * BATCH + b0 + tb * 4 + bi];
  float P[4][4];
  float* hw = h + ((size_t)s * BATCH + b0) * HDIM;
  float* cw = c + ((size_t)s * BATCH + b0) * HDIM;
  const int order[4] = {0, 2, 1, 3};
#pragma unroll 1
  for (int cc = 0; cc < 4; ++cc) {
    const int chunk = order[cc];
    const int g0 = chunk * HDIM + tg * 4;
    float acc[4][4] = {};
    const float* wh = WtHd + (size_t)s * HDIM * G4H + g0;
    for (int k = 0; k < HDIM; k += 4) {
      float4 xv[4];
#pragma unroll
      for (int bi = 0; bi < 4; ++bi) xv[bi] = *(const float4*)(&hs[tb * 4 + bi][k]);
      const float* w0 = wh + (size_t)k * G4H;
#pragma unroll
      for (int kk = 0; kk < 4; ++kk) {
        const float4 w = *(const float4*)(w0 + (size_t)kk * G4H);
#pragma unroll
        for (int bi = 0; bi < 4; ++bi) {
          const float xk = ((const float*)&xv[bi])[kk];
          acc[bi][0] = fmaf(xk, w.x, acc[bi][0]);
          acc[bi][1] = fmaf(xk, w.y, acc[bi][1]);
          acc[bi][2] = fmaf(xk, w.z, acc[bi][2]);
          acc[bi][3] = fmaf(xk, w.w, acc[bi][3]);
        }
      }
    }
#pragma unroll
    for (int bi = 0; bi < 4; ++bi) {
      const int bb = tb * 4 + bi;
#pragma unroll
      for (int gj = 0; gj < 4; ++gj) {
        const int gidx = g0 + gj;
        const int j = gidx - chunk * HDIM;
        float gate = acc[bi][gj] + it[bi] * Wihd[s * G4H + gidx]
                     + bihd[s * G4H + gidx] + bhhd[s * G4H + gidx];
        if (cc == 0) {
          P[bi][gj] = sigf(gate);
        } else if (cc == 1) {
          P[bi][gj] *= tanhf(gate);
        } else if (cc == 2) {
          float cn = fmaf(sigf(gate), cw[(size_t)bb * HDIM + j], P[bi][gj]);
          cw[(size_t)bb * HDIM + j] = cn;
          P[bi][gj] = tanhf(cn);
        } else {
          float hn_ = sigf(gate) * P[bi][gj];
          hw[(size_t)bb * HDIM + j] = hn_;
          P[bi][gj] = hn_;
        }
      }
    }
  }
  __syncthreads();
#pragma unroll
  for (int bi = 0; bi < 4; ++bi)
#pragma unroll
    for (int gj = 0; gj < 4; ++gj) hn[tb * 4 + bi][tg * 4 + gj] = P[bi][gj];
  __syncthreads();

  // scores: per (b, t): h_new . kp_t + kb_t, then softmax over t
  {
    const int bb = tid & 15, tt = tid >> 4;
    if (tt < TENC) {
      const float* kpr = kp + (((size_t)tt * S8 + s) * BATCH + b0 + bb) * HDIM;
      float a = 0.f;
      for (int k = 0; k < HDIM; k += 4) {
        const float4 kk = *(const float4*)(kpr + k);
        const float4 hh = *(const float4*)(&hn[bb][k]);
        a = fmaf(kk.x, hh.x, a); a = fmaf(kk.y, hh.y, a);
        a = fmaf(kk.z, hh.z, a); a = fmaf(kk.w, hh.w, a);
      }
      a += kb[((size_t)tt * S8 + s) * BATCH + b0 + bb];
      sc[bb][tt] = a * SCALE_ATTN;
    }
  }
  __syncthreads();
  if (tid < BT) {
    float m = sc[tid][0];
#pragma unroll
    for (int t2 = 1; t2 < TENC; ++t2) m = fmaxf(m, sc[tid][t2]);
    float e[TENC], sum = 0.f;
#pragma unroll
    for (int t2 = 0; t2 < TENC; ++t2) { e[t2] = expf(sc[tid][t2] - m); sum += e[t2]; }
    const float inv = 1.0f / sum;
#pragma unroll
    for (int t2 = 0; t2 < TENC; ++t2) sc[tid][t2] = e[t2] * inv;
  }
  __syncthreads();

  // ctx (pre-projected) + out_fc
  {
    const int bb = tid >> 4, p = tid & 15, e0 = p * 16;
    float ctx[16];
#pragma unroll
    for (int ei = 0; ei < 16; ++ei) ctx[ei] = cbias[s * HDIM + e0 + ei];
    for (int tt = 0; tt < TENC; ++tt) {
      const float a = sc[bb][tt];
      const float* vpr = vp + (((size_t)tt * S8 + s) * BATCH + b0 + bb) * HDIM + e0;
#pragma unroll
      for (int ei = 0; ei < 16; ei += 4) {
        const float4 vv = *(const float4*)(vpr + ei);
        ctx[ei]     = fmaf(a, vv.x, ctx[ei]);
        ctx[ei + 1] = fmaf(a, vv.y, ctx[ei + 1]);
        ctx[ei + 2] = fmaf(a, vv.z, ctx[ei + 2]);
        ctx[ei + 3] = fmaf(a, vv.w, ctx[ei + 3]);
      }
    }
    float part = 0.f;
    const float* wf = Wfo + s * 512;
#pragma unroll
    for (int ei = 0; ei < 16; ++ei) part = fmaf(ctx[ei], wf[HDIM + e0 + ei], part);
#pragma unroll
    for (int ki = 0; ki < 16; ++ki) part = fmaf(hn[bb][e0 + ki], wf[e0 + ki], part);
    red[bb][p] = part;
  }
  __syncthreads();
  if (tid < BT) {
    float a = 0.f;
#pragma unroll
    for (int p = 0; p < 16; ++p) a += red[tid][p];
    douts[((size_t)l * S8 + s) * BATCH + b0 + tid] = a + bfo[s];
  }
}

// ---------------- final fc over streams ----------------
__global__ void final_fc(const float* __restrict__ douts, const float* __restrict__ Wfc,
                         const float* __restrict__ bfc, float* __restrict__ out) {
  int idx = blockIdx.x * 256 + threadIdx.x;
  if (idx >= BATCH * LDEC) return;
  int b = idx / LDEC, l = idx - b * LDEC;
  float a = bfc[0];
#pragma unroll
  for (int s = 0; s < S8; ++s)
    a = fmaf(douts[((size_t)l * S8 + s) * BATCH + b], Wfc[s], a);
  out[idx] = a;
}

extern "C" void kernel_launch(void* const* d_in, const int* in_sizes, int n_in,
                              void* d_out, int out_size, void* d_ws, size_t ws_size,
                              hipStream_t stream) {
  const float* x          = (const float*)d_in[0];
  const float* tgt        = (const float*)d_in[1];
  const float* W_ih_e     = (const float*)d_in[2];
  const float* W_hh_e     = (const float*)d_in[3];
  const float* b_ih_e     = (const float*)d_in[4];
  const float* b_hh_e     = (const float*)d_in[5];
  const float* W_ih_d     = (const float*)d_in[6];
  const float* W_hh_d     = (const float*)d_in[7];
  const float* b_ih_d     = (const float*)d_in[8];
  const float* b_hh_d     = (const float*)d_in[9];
  const float* W_in_attn  = (const float*)d_in[10];
  const float* b_in_attn  = (const float*)d_in[11];
  const float* W_out_attn = (const float*)d_in[12];
  const float* b_out_attn = (const float*)d_in[13];
  const float* W_fcout    = (const float*)d_in[14];
  const float* b_fcout    = (const float*)d_in[15];
  const float* W_fc       = (const float*)d_in[16];
  const float* b_fc       = (const float*)d_in[17];

  float* ws = (float*)d_ws;
  size_t off = 0;
  auto alloc = [&](size_t n) { float* p = ws + off; off += n; return p; };
  float* kp    = alloc((size_t)TENC * S8 * BATCH * HDIM);
  float* vp    = alloc((size_t)TENC * S8 * BATCH * HDIM);
  float* kb    = alloc((size_t)TENC * S8 * BATCH);
  float* h     = alloc((size_t)S8 * BATCH * HDIM);
  float* c     = alloc((size_t)S8 * BATCH * HDIM);
  float* douts = alloc((size_t)LDEC * S8 * BATCH);
  float* decin = alloc((size_t)LDEC * BATCH);
  float* WtX   = alloc((size_t)S8 * FDIM * G4H);
  float* WtHe  = alloc((size_t)S8 * HDIM * G4H);
  float* WtHd  = alloc((size_t)S8 * HDIM * G4H);
  float* WoT   = alloc((size_t)S8 * HDIM * HDIM);
  float* MkT   = alloc((size_t)S8 * HDIM * HDIM);
  float* MvT   = alloc((size_t)S8 * HDIM * HDIM);
  float* kbv   = alloc((size_t)S8 * HDIM);
  float* cbias = alloc((size_t)S8 * HDIM);
  if (off * sizeof(float) > ws_size) {
    fprintf(stderr, "kernel_launch: ws too small: need %zu bytes, have %zu\n",
            off * sizeof(float), ws_size);
    return;
  }

  // zero h and c (contiguous in ws)
  hipMemsetAsync(h, 0, (size_t)2 * S8 * BATCH * HDIM * sizeof(float), stream);

  // one-time weight transposes (coalesced GEMM access later)
  transpose_k<<<dim3(10, 32, S8), 256, 0, stream>>>(W_ih_e, WtX, G4H, FDIM);
  transpose_k<<<dim3(8, 32, S8), 256, 0, stream>>>(W_hh_e, WtHe, G4H, HDIM);
  transpose_k<<<dim3(8, 32, S8), 256, 0, stream>>>(W_hh_d, WtHd, G4H, HDIM);
  transpose_k<<<dim3(8, 8, S8), 256, 0, stream>>>(W_out_attn, WoT, HDIM, HDIM);

  // attention folds: M_k = Wq^T Wk (stored [h2][h]); M_v = W_out Wv (stored [h2][o])
  fold_gemm<<<dim3(8, S8), 256, 0, stream>>>(W_in_attn + 256 * 256, (size_t)768 * 256,
                                             W_in_attn, (size_t)768 * 256,
                                             MkT, (size_t)HDIM * HDIM);
  fold_gemm<<<dim3(8, S8), 256, 0, stream>>>(W_in_attn + 2 * 256 * 256, (size_t)768 * 256,
                                             WoT, (size_t)HDIM * HDIM,
                                             MvT, (size_t)HDIM * HDIM);
  fold_vec<<<S8, 256, 0, stream>>>(W_in_attn, b_in_attn, WoT, b_out_attn, kbv, cbias);
  build_decin<<<(LDEC * BATCH + 255) / 256, 256, 0, stream>>>(x, tgt, decin);

  for (int t = 0; t < TENC; ++t)
    enc_step<<<dim3(BATCH / BT, S8), 256, 0, stream>>>(
        x, WtX, WtHe, b_ih_e, b_hh_e, MkT, MvT, kbv, h, c, kp, vp, kb, t);

  for (int l = 0; l < LDEC; ++l)
    dec_step<<<dim3(BATCH / BT, S8), 256, 0, stream>>>(
        WtHd, W_ih_d, b_ih_d, b_hh_d, kp, vp, kb, cbias,
        W_fcout, b_fcout, decin, h, c, douts, l);

  final_fc<<<(BATCH * LDEC + 255) / 256, 256, 0, stream>>>(douts, W_fc, b_fc, (float*)d_out);
}

// Round 2
// 11971.622 us; speedup vs baseline: 1.0450x; 1.0450x over previous
//
#include <hip/hip_runtime.h>
#include <cstdio>
#include <cstdint>

#define S8     8
#define TENC   12
#define HDIM   256
#define FDIM   316
#define BATCH  1024
#define LDEC   48
#define G4H    1024
#define BT     16          // encoder batch tile
#define DBT    32          // decoder batch tile
#define SCALE_ATTN 0.0625f // 1/sqrt(256)

__device__ __forceinline__ float sigf(float x) { return 1.0f / (1.0f + expf(-x)); }

__device__ __forceinline__ unsigned short f2bf(float f) {
  unsigned u = __builtin_bit_cast(unsigned, f);
  unsigned r = (u + 0x7fffu + ((u >> 16) & 1u)) >> 16;   // RNE
  return (unsigned short)r;
}
__device__ __forceinline__ float bflo(unsigned u) {
  return __builtin_bit_cast(float, u << 16);
}
__device__ __forceinline__ float bfhi(unsigned u) {
  return __builtin_bit_cast(float, u & 0xffff0000u);
}

// ---------------- transpose: in [S][R][C] -> out [S][C][R] ----------------
__global__ __launch_bounds__(256) void transpose_k(const float* __restrict__ in,
                                                   float* __restrict__ out,
                                                   int R, int C) {
  __shared__ float tile[32][33];
  const int s = blockIdx.z;
  const size_t base = (size_t)s * R * C;
  const int r0 = blockIdx.y * 32, c0 = blockIdx.x * 32;
  const int tx = threadIdx.x & 31, ty = threadIdx.x >> 5;
  for (int i = ty; i < 32; i += 8) {
    int r = r0 + i, c = c0 + tx;
    if (r < R && c < C) tile[i][tx] = in[base + (size_t)r * C + c];
  }
  __syncthreads();
  for (int i = ty; i < 32; i += 8) {
    int c = c0 + i, r = r0 + tx;
    if (c < C && r < R) out[base + (size_t)c * R + r] = tile[tx][i];
  }
}

// ---- fold GEMM: out[s][r][col] = sum_e A[s][e][r] * B[s][e][col], 256x256, K=256 ----
__global__ __launch_bounds__(256) void fold_gemm(const float* __restrict__ A, size_t sA,
                                                 const float* __restrict__ Bm, size_t sB,
                                                 float* __restrict__ out, size_t sO) {
  const int s = blockIdx.y, r0 = blockIdx.x * 32, col = threadIdx.x;
  A += (size_t)s * sA; Bm += (size_t)s * sB; out += (size_t)s * sO;
  float acc[32] = {};
  for (int e = 0; e < HDIM; ++e) {
    const float bvv = Bm[(size_t)e * HDIM + col];
#pragma unroll
    for (int r = 0; r < 32; ++r) acc[r] = fmaf(A[(size_t)e * HDIM + r0 + r], bvv, acc[r]);
  }
  for (int r = 0; r < 32; ++r) out[(size_t)(r0 + r) * HDIM + col] = acc[r];
}

// ---- fold vectors: kbv[s][h2] = Wk^T bq ; cbias[s][o] = W_out bv + b_out ----
__global__ __launch_bounds__(256) void fold_vec(const float* __restrict__ W_in_attn,
                                                const float* __restrict__ b_in_attn,
                                                const float* __restrict__ WoT,
                                                const float* __restrict__ b_out_attn,
                                                float* __restrict__ kbv,
                                                float* __restrict__ cbias) {
  const int s = blockIdx.x, t = threadIdx.x;
  const float* Wk = W_in_attn + (size_t)s * 768 * 256 + 256 * 256;
  const float* bq = b_in_attn + (size_t)s * 768;
  const float* bv = b_in_attn + (size_t)s * 768 + 512;
  const float* Wo = WoT + (size_t)s * 256 * 256;
  float a0 = 0.f, a1 = 0.f;
  for (int e = 0; e < 256; ++e) {
    a0 = fmaf(Wk[(size_t)e * 256 + t], bq[e], a0);
    a1 = fmaf(Wo[(size_t)e * 256 + t], bv[e], a1);
  }
  kbv[s * 256 + t] = a0;
  cbias[s * 256 + t] = a1 + b_out_attn[s * 256 + t];
}

// ---- decoder teacher-forced inputs ----
__global__ void build_decin(const float* __restrict__ x, const float* __restrict__ tgt,
                            float* __restrict__ dec_in) {
  int idx = blockIdx.x * 256 + threadIdx.x;
  if (idx >= LDEC * BATCH) return;
  int l = idx >> 10, b = idx & 1023;
  dec_in[idx] = (l == 0) ? x[(size_t)b * 96 * FDIM + 95 * FDIM]
                         : tgt[(size_t)b * LDEC + (l - 1)];
}

// ---------------- encoder step ----------------
__global__ __launch_bounds__(256) void enc_step(
    const float* __restrict__ x,
    const float* __restrict__ WtX,    // [S][316][1024]
    const float* __restrict__ WtH,    // [S][256][1024]
    const float* __restrict__ bihe, const float* __restrict__ bhhe,
    const float* __restrict__ MkT,    // [S][256][256]
    const float* __restrict__ MvT,    // [S][256][256]
    const float* __restrict__ kbv,    // [S][256]
    float* __restrict__ h, float* __restrict__ c,          // [S][B][256]
    unsigned short* __restrict__ kp,  // [T][S][B][256] bf16
    unsigned short* __restrict__ vp,  // [T][S][B][256] bf16
    float* __restrict__ kb,           // [T][S][B]
    int t) {
  __shared__ float xs[BT][320];
  __shared__ float hs[BT][256];
  __shared__ float red[16][16];
  const int s = blockIdx.y, b0 = blockIdx.x * BT;
  const int tid = threadIdx.x;

  {
    const float* xb = x + (size_t)(s * TENC + t) * FDIM;
    for (int i = tid; i < BT * FDIM; i += 256) {
      int bb = i / FDIM, f = i - bb * FDIM;
      xs[bb][f] = xb[(size_t)(b0 + bb) * (96 * FDIM) + f];
    }
    const float* hb = h + ((size_t)s * BATCH + b0) * HDIM;
    for (int i = tid; i < BT * HDIM; i += 256) hs[i >> 8][i & 255] = hb[i];
  }
  __syncthreads();

  const int tg = tid & 63, tb = tid >> 6;
  float P[4][4];
  float* hw = h + ((size_t)s * BATCH + b0) * HDIM;
  float* cw = c + ((size_t)s * BATCH + b0) * HDIM;
  const int order[4] = {0, 2, 1, 3};        // i, g, f, o
#pragma unroll 1
  for (int cc = 0; cc < 4; ++cc) {
    const int chunk = order[cc];
    const int g0 = chunk * HDIM + tg * 4;
    float acc[4][4] = {};
    {
      const float* wx = WtX + (size_t)s * FDIM * G4H + g0;
      for (int k = 0; k < FDIM; k += 4) {
        float4 xv[4];
#pragma unroll
        for (int bi = 0; bi < 4; ++bi) xv[bi] = *(const float4*)(&xs[tb * 4 + bi][k]);
        const float* w0 = wx + (size_t)k * G4H;
#pragma unroll
        for (int kk = 0; kk < 4; ++kk) {
          const float4 w = *(const float4*)(w0 + (size_t)kk * G4H);
#pragma unroll
          for (int bi = 0; bi < 4; ++bi) {
            const float xk = ((const float*)&xv[bi])[kk];
            acc[bi][0] = fmaf(xk, w.x, acc[bi][0]);
            acc[bi][1] = fmaf(xk, w.y, acc[bi][1]);
            acc[bi][2] = fmaf(xk, w.z, acc[bi][2]);
            acc[bi][3] = fmaf(xk, w.w, acc[bi][3]);
          }
        }
      }
    }
    {
      const float* wh = WtH + (size_t)s * HDIM * G4H + g0;
      for (int k = 0; k < HDIM; k += 4) {
        float4 xv[4];
#pragma unroll
        for (int bi = 0; bi < 4; ++bi) xv[bi] = *(const float4*)(&hs[tb * 4 + bi][k]);
        const float* w0 = wh + (size_t)k * G4H;
#pragma unroll
        for (int kk = 0; kk < 4; ++kk) {
          const float4 w = *(const float4*)(w0 + (size_t)kk * G4H);
#pragma unroll
          for (int bi = 0; bi < 4; ++bi) {
            const float xk = ((const float*)&xv[bi])[kk];
            acc[bi][0] = fmaf(xk, w.x, acc[bi][0]);
            acc[bi][1] = fmaf(xk, w.y, acc[bi][1]);
            acc[bi][2] = fmaf(xk, w.z, acc[bi][2]);
            acc[bi][3] = fmaf(xk, w.w, acc[bi][3]);
          }
        }
      }
    }
#pragma unroll
    for (int bi = 0; bi < 4; ++bi) {
      const int bb = tb * 4 + bi;
#pragma unroll
      for (int gj = 0; gj < 4; ++gj) {
        const int gidx = g0 + gj;
        const int j = gidx - chunk * HDIM;
        float gate = acc[bi][gj] + bihe[s * G4H + gidx] + bhhe[s * G4H + gidx];
        if (cc == 0) {
          P[bi][gj] = sigf(gate);
        } else if (cc == 1) {
          P[bi][gj] *= tanhf(gate);
        } else if (cc == 2) {
          float cn = fmaf(sigf(gate), cw[(size_t)bb * HDIM + j], P[bi][gj]);
          cw[(size_t)bb * HDIM + j] = cn;
          P[bi][gj] = tanhf(cn);
        } else {
          float hn = sigf(gate) * P[bi][gj];
          hw[(size_t)bb * HDIM + j] = hn;
          P[bi][gj] = hn;
        }
      }
    }
  }
  __syncthreads();
#pragma unroll
  for (int bi = 0; bi < 4; ++bi)
#pragma unroll
    for (int gj = 0; gj < 4; ++gj) hs[tb * 4 + bi][tg * 4 + gj] = P[bi][gj];
  __syncthreads();

  // kp / vp projections (bf16 stores)
  {
    const int c0 = tg * 4;
    float a1[4][4] = {}, a2[4][4] = {};
    const float* mk = MkT + (size_t)s * HDIM * HDIM + c0;
    const float* mv = MvT + (size_t)s * HDIM * HDIM + c0;
    for (int k = 0; k < HDIM; k += 4) {
      float4 xv[4];
#pragma unroll
      for (int bi = 0; bi < 4; ++bi) xv[bi] = *(const float4*)(&hs[tb * 4 + bi][k]);
#pragma unroll
      for (int kk = 0; kk < 4; ++kk) {
        const float4 wk4 = *(const float4*)(mk + (size_t)(k + kk) * HDIM);
        const float4 wv4 = *(const float4*)(mv + (size_t)(k + kk) * HDIM);
#pragma unroll
        for (int bi = 0; bi < 4; ++bi) {
          const float hv = ((const float*)&xv[bi])[kk];
          a1[bi][0] = fmaf(hv, wk4.x, a1[bi][0]);
          a1[bi][1] = fmaf(hv, wk4.y, a1[bi][1]);
          a1[bi][2] = fmaf(hv, wk4.z, a1[bi][2]);
          a1[bi][3] = fmaf(hv, wk4.w, a1[bi][3]);
          a2[bi][0] = fmaf(hv, wv4.x, a2[bi][0]);
          a2[bi][1] = fmaf(hv, wv4.y, a2[bi][1]);
          a2[bi][2] = fmaf(hv, wv4.z, a2[bi][2]);
          a2[bi][3] = fmaf(hv, wv4.w, a2[bi][3]);
        }
      }
    }
    unsigned short* kpw = kp + (((size_t)t * S8 + s) * BATCH + b0) * HDIM;
    unsigned short* vpw = vp + (((size_t)t * S8 + s) * BATCH + b0) * HDIM;
#pragma unroll
    for (int bi = 0; bi < 4; ++bi) {
      const int bb = tb * 4 + bi;
      ushort4 pk, pv;
      pk.x = f2bf(a1[bi][0]); pk.y = f2bf(a1[bi][1]);
      pk.z = f2bf(a1[bi][2]); pk.w = f2bf(a1[bi][3]);
      pv.x = f2bf(a2[bi][0]); pv.y = f2bf(a2[bi][1]);
      pv.z = f2bf(a2[bi][2]); pv.w = f2bf(a2[bi][3]);
      *(ushort4*)(&kpw[(size_t)bb * HDIM + c0]) = pk;
      *(ushort4*)(&vpw[(size_t)bb * HDIM + c0]) = pv;
    }
  }
  // kb = kbv . h_new
  {
    const int bb = tid >> 4, p = tid & 15;
    float a = 0.f;
    const float* kv = kbv + s * HDIM;
    for (int k = p * 16; k < p * 16 + 16; ++k) a = fmaf(kv[k], hs[bb][k], a);
    red[bb][p] = a;
  }
  __syncthreads();
  if (tid < BT) {
    float a = 0.f;
#pragma unroll
    for (int p = 0; p < 16; ++p) a += red[tid][p];
    kb[((size_t)t * S8 + s) * BATCH + b0 + tid] = a;
  }
}

// ---------------- decoder step (fully fused, 512 threads, 32-batch tile) ----------------
__global__ __launch_bounds__(512, 2) void dec_step(
    const float* __restrict__ WtHd,   // [S][256][1024]
    const float* __restrict__ Wihd,   // [S][1024]
    const float* __restrict__ bihd, const float* __restrict__ bhhd,
    const unsigned short* __restrict__ kp,  // [T][S][B][256] bf16
    const unsigned short* __restrict__ vp,  // [T][S][B][256] bf16
    const float* __restrict__ kb,           // [T][S][B]
    const float* __restrict__ cbias,  // [S][256]
    const float* __restrict__ Wfo,    // [S][512]
    const float* __restrict__ bfo,    // [S]
    const float* __restrict__ decin,  // [L][B]
    float* __restrict__ h, float* __restrict__ c,
    float* __restrict__ douts,        // [L][S][B]
    int l) {
  __shared__ float hs[DBT][256];      // old h (float4, broadcast reads)
  __shared__ float hn[DBT][257];      // new h (padded: conflict-free score dots)
  __shared__ float sc[DBT][12];
  __shared__ float red[DBT][16];
  const int s = blockIdx.y, b0 = blockIdx.x * DBT;
  const int tid = threadIdx.x;
  {
    const float4* hb = (const float4*)(h + ((size_t)s * BATCH + b0) * HDIM);
    float4* hd = (float4*)hs;
    for (int i = tid; i < DBT * HDIM / 4; i += 512) hd[i] = hb[i];
  }
  __syncthreads();

  const int tg = tid & 63, tb = tid >> 6;   // 64 gate-threads x 8 row-groups
  float it[4];
#pragma unroll
  for (int bi = 0; bi < 4; ++bi) it[bi] = decin[(size_t)l * BATCH + b0 + tb * 4 + bi];
  float P[4][4];
  float* hw = h + ((size_t)s * BATCH + b0) * HDIM;
  float* cw = c + ((size_t)s * BATCH + b0) * HDIM;
  const int order[4] = {0, 2, 1, 3};
#pragma unroll 1
  for (int cc = 0; cc < 4; ++cc) {
    const int chunk = order[cc];
    const int g0 = chunk * HDIM + tg * 4;
    float acc[4][4] = {};
    const float* wh = WtHd + (size_t)s * HDIM * G4H + g0;
    for (int k = 0; k < HDIM; k += 4) {
      float4 xv[4];
#pragma unroll
      for (int bi = 0; bi < 4; ++bi) xv[bi] = *(const float4*)(&hs[tb * 4 + bi][k]);
      const float* w0 = wh + (size_t)k * G4H;
#pragma unroll
      for (int kk = 0; kk < 4; ++kk) {
        const float4 w = *(const float4*)(w0 + (size_t)kk * G4H);
#pragma unroll
        for (int bi = 0; bi < 4; ++bi) {
          const float xk = ((const float*)&xv[bi])[kk];
          acc[bi][0] = fmaf(xk, w.x, acc[bi][0]);
          acc[bi][1] = fmaf(xk, w.y, acc[bi][1]);
          acc[bi][2] = fmaf(xk, w.z, acc[bi][2]);
          acc[bi][3] = fmaf(xk, w.w, acc[bi][3]);
        }
      }
    }
#pragma unroll
    for (int bi = 0; bi < 4; ++bi) {
      const int bb = tb * 4 + bi;
      const int j0 = tg * 4;
      if (cc == 0) {
#pragma unroll
        for (int gj = 0; gj < 4; ++gj) {
          const int gidx = g0 + gj;
          float gate = acc[bi][gj] + it[bi] * Wihd[s * G4H + gidx]
                       + bihd[s * G4H + gidx] + bhhd[s * G4H + gidx];
          P[bi][gj] = sigf(gate);
        }
      } else if (cc == 1) {
#pragma unroll
        for (int gj = 0; gj < 4; ++gj) {
          const int gidx = g0 + gj;
          float gate = acc[bi][gj] + it[bi] * Wihd[s * G4H + gidx]
                       + bihd[s * G4H + gidx] + bhhd[s * G4H + gidx];
          P[bi][gj] *= tanhf(gate);
        }
      } else if (cc == 2) {
        const float4 cold = *(const float4*)(cw + (size_t)bb * HDIM + j0);
        float4 cnew;
#pragma unroll
        for (int gj = 0; gj < 4; ++gj) {
          const int gidx = g0 + gj;
          float gate = acc[bi][gj] + it[bi] * Wihd[s * G4H + gidx]
                       + bihd[s * G4H + gidx] + bhhd[s * G4H + gidx];
          float cn = fmaf(sigf(gate), ((const float*)&cold)[gj], P[bi][gj]);
          ((float*)&cnew)[gj] = cn;
          P[bi][gj] = tanhf(cn);
        }
        *(float4*)(cw + (size_t)bb * HDIM + j0) = cnew;
      } else {
        float4 hnew;
#pragma unroll
        for (int gj = 0; gj < 4; ++gj) {
          const int gidx = g0 + gj;
          float gate = acc[bi][gj] + it[bi] * Wihd[s * G4H + gidx]
                       + bihd[s * G4H + gidx] + bhhd[s * G4H + gidx];
          float hv = sigf(gate) * P[bi][gj];
          ((float*)&hnew)[gj] = hv;
          P[bi][gj] = hv;
        }
        *(float4*)(hw + (size_t)bb * HDIM + j0) = hnew;
      }
    }
  }
  __syncthreads();
#pragma unroll
  for (int bi = 0; bi < 4; ++bi)
#pragma unroll
    for (int gj = 0; gj < 4; ++gj) hn[tb * 4 + bi][tg * 4 + gj] = P[bi][gj];
  __syncthreads();

  // scores: (b 32) x (t 12) threads, each a full 256-dot on bf16 kp
  {
    const int bb = tid & 31, tt = tid >> 5;
    if (tt < TENC) {
      const uint4* kpr = (const uint4*)(kp + (((size_t)tt * S8 + s) * BATCH + b0 + bb) * HDIM);
      float a = 0.f;
#pragma unroll 4
      for (int k = 0; k < HDIM / 8; ++k) {
        const uint4 q = kpr[k];
        const float* hh = &hn[bb][k * 8];
        a = fmaf(bflo(q.x), hh[0], a); a = fmaf(bfhi(q.x), hh[1], a);
        a = fmaf(bflo(q.y), hh[2], a); a = fmaf(bfhi(q.y), hh[3], a);
        a = fmaf(bflo(q.z), hh[4], a); a = fmaf(bfhi(q.z), hh[5], a);
        a = fmaf(bflo(q.w), hh[6], a); a = fmaf(bfhi(q.w), hh[7], a);
      }
      a += kb[((size_t)tt * S8 + s) * BATCH + b0 + bb];
      sc[bb][tt] = a * SCALE_ATTN;
    }
  }
  __syncthreads();
  if (tid < DBT) {
    float m = sc[tid][0];
#pragma unroll
    for (int t2 = 1; t2 < TENC; ++t2) m = fmaxf(m, sc[tid][t2]);
    float e[TENC], sum = 0.f;
#pragma unroll
    for (int t2 = 0; t2 < TENC; ++t2) { e[t2] = expf(sc[tid][t2] - m); sum += e[t2]; }
    const float inv = 1.0f / sum;
#pragma unroll
    for (int t2 = 0; t2 < TENC; ++t2) sc[tid][t2] = e[t2] * inv;
  }
  __syncthreads();

  // ctx (pre-projected, bf16 vp) + out_fc : (b 32) x (p 16) threads, 16 dims each
  {
    const int bb = tid >> 4, p = tid & 15, e0 = p * 16;
    float ctx[16];
#pragma unroll
    for (int ei = 0; ei < 16; ++ei) ctx[ei] = cbias[s * HDIM + e0 + ei];
    for (int tt = 0; tt < TENC; ++tt) {
      const float a = sc[bb][tt];
      const uint4* vpr = (const uint4*)(vp + (((size_t)tt * S8 + s) * BATCH + b0 + bb) * HDIM + e0);
#pragma unroll
      for (int half = 0; half < 2; ++half) {
        const uint4 q = vpr[half];
        const int e = half * 8;
        ctx[e]     = fmaf(a, bflo(q.x), ctx[e]);
        ctx[e + 1] = fmaf(a, bfhi(q.x), ctx[e + 1]);
        ctx[e + 2] = fmaf(a, bflo(q.y), ctx[e + 2]);
        ctx[e + 3] = fmaf(a, bfhi(q.y), ctx[e + 3]);
        ctx[e + 4] = fmaf(a, bflo(q.z), ctx[e + 4]);
        ctx[e + 5] = fmaf(a, bfhi(q.z), ctx[e + 5]);
        ctx[e + 6] = fmaf(a, bflo(q.w), ctx[e + 6]);
        ctx[e + 7] = fmaf(a, bfhi(q.w), ctx[e + 7]);
      }
    }
    float part = 0.f;
    const float* wf = Wfo + s * 512;
#pragma unroll
    for (int ei = 0; ei < 16; ++ei) part = fmaf(ctx[ei], wf[HDIM + e0 + ei], part);
#pragma unroll
    for (int ki = 0; ki < 16; ++ki) part = fmaf(hn[bb][e0 + ki], wf[e0 + ki], part);
    red[bb][p] = part;
  }
  __syncthreads();
  if (tid < DBT) {
    float a = 0.f;
#pragma unroll
    for (int p = 0; p < 16; ++p) a += red[tid][p];
    douts[((size_t)l * S8 + s) * BATCH + b0 + tid] = a + bfo[s];
  }
}

// ---------------- final fc over streams ----------------
__global__ void final_fc(const float* __restrict__ douts, const float* __restrict__ Wfc,
                         const float* __restrict__ bfc, float* __restrict__ out) {
  int idx = blockIdx.x * 256 + threadIdx.x;
  if (idx >= BATCH * LDEC) return;
  int b = idx / LDEC, l = idx - b * LDEC;
  float a = bfc[0];
#pragma unroll
  for (int s = 0; s < S8; ++s)
    a = fmaf(douts[((size_t)l * S8 + s) * BATCH + b], Wfc[s], a);
  out[idx] = a;
}

extern "C" void kernel_launch(void* const* d_in, const int* in_sizes, int n_in,
                              void* d_out, int out_size, void* d_ws, size_t ws_size,
                              hipStream_t stream) {
  const float* x          = (const float*)d_in[0];
  const float* tgt        = (const float*)d_in[1];
  const float* W_ih_e     = (const float*)d_in[2];
  const float* W_hh_e     = (const float*)d_in[3];
  const float* b_ih_e     = (const float*)d_in[4];
  const float* b_hh_e     = (const float*)d_in[5];
  const float* W_ih_d     = (const float*)d_in[6];
  const float* W_hh_d     = (const float*)d_in[7];
  const float* b_ih_d     = (const float*)d_in[8];
  const float* b_hh_d     = (const float*)d_in[9];
  const float* W_in_attn  = (const float*)d_in[10];
  const float* b_in_attn  = (const float*)d_in[11];
  const float* W_out_attn = (const float*)d_in[12];
  const float* b_out_attn = (const float*)d_in[13];
  const float* W_fcout    = (const float*)d_in[14];
  const float* b_fcout    = (const float*)d_in[15];
  const float* W_fc       = (const float*)d_in[16];
  const float* b_fc       = (const float*)d_in[17];

  char* wsb = (char*)d_ws;
  size_t off = 0;
  auto alloc = [&](size_t bytes) {
    void* p = wsb + off; off += (bytes + 255) & ~(size_t)255; return p;
  };
  unsigned short* kp = (unsigned short*)alloc((size_t)TENC * S8 * BATCH * HDIM * 2);
  unsigned short* vp = (unsigned short*)alloc((size_t)TENC * S8 * BATCH * HDIM * 2);
  float* kb    = (float*)alloc((size_t)TENC * S8 * BATCH * 4);
  float* h     = (float*)alloc((size_t)S8 * BATCH * HDIM * 4);
  float* c     = (float*)alloc((size_t)S8 * BATCH * HDIM * 4);
  float* douts = (float*)alloc((size_t)LDEC * S8 * BATCH * 4);
  float* decin = (float*)alloc((size_t)LDEC * BATCH * 4);
  float* WtX   = (float*)alloc((size_t)S8 * FDIM * G4H * 4);
  float* WtHe  = (float*)alloc((size_t)S8 * HDIM * G4H * 4);
  float* WtHd  = (float*)alloc((size_t)S8 * HDIM * G4H * 4);
  float* WoT   = (float*)alloc((size_t)S8 * HDIM * HDIM * 4);
  float* MkT   = (float*)alloc((size_t)S8 * HDIM * HDIM * 4);
  float* MvT   = (float*)alloc((size_t)S8 * HDIM * HDIM * 4);
  float* kbv   = (float*)alloc((size_t)S8 * HDIM * 4);
  float* cbias = (float*)alloc((size_t)S8 * HDIM * 4);
  if (off > ws_size) {
    fprintf(stderr, "kernel_launch: ws too small: need %zu bytes, have %zu\n", off, ws_size);
    return;
  }

  hipMemsetAsync(h, 0, (size_t)2 * S8 * BATCH * HDIM * sizeof(float), stream);

  transpose_k<<<dim3(10, 32, S8), 256, 0, stream>>>(W_ih_e, WtX, G4H, FDIM);
  transpose_k<<<dim3(8, 32, S8), 256, 0, stream>>>(W_hh_e, WtHe, G4H, HDIM);
  transpose_k<<<dim3(8, 32, S8), 256, 0, stream>>>(W_hh_d, WtHd, G4H, HDIM);
  transpose_k<<<dim3(8, 8, S8), 256, 0, stream>>>(W_out_attn, WoT, HDIM, HDIM);

  fold_gemm<<<dim3(8, S8), 256, 0, stream>>>(W_in_attn + 256 * 256, (size_t)768 * 256,
                                             W_in_attn, (size_t)768 * 256,
                                             MkT, (size_t)HDIM * HDIM);
  fold_gemm<<<dim3(8, S8), 256, 0, stream>>>(W_in_attn + 2 * 256 * 256, (size_t)768 * 256,
                                             WoT, (size_t)HDIM * HDIM,
                                             MvT, (size_t)HDIM * HDIM);
  fold_vec<<<S8, 256, 0, stream>>>(W_in_attn, b_in_attn, WoT, b_out_attn, kbv, cbias);
  build_decin<<<(LDEC * BATCH + 255) / 256, 256, 0, stream>>>(x, tgt, decin);

  for (int t = 0; t < TENC; ++t)
    enc_step<<<dim3(BATCH / BT, S8), 256, 0, stream>>>(
        x, WtX, WtHe, b_ih_e, b_hh_e, MkT, MvT, kbv, h, c, kp, vp, kb, t);

  for (int l = 0; l < LDEC; ++l)
    dec_step<<<dim3(BATCH / DBT, S8), 512, 0, stream>>>(
        WtHd, W_ih_d, b_ih_d, b_hh_d, kp, vp, kb, cbias,
        W_fcout, b_fcout, decin, h, c, douts, l);

  final_fc<<<(BATCH * LDEC + 255) / 256, 256, 0, stream>>>(douts, W_fc, b_fc, (float*)d_out);
}

// Round 4
// 6521.872 us; speedup vs baseline: 1.9181x; 1.8356x over previous
//
#include <hip/hip_runtime.h>
#include <cstdio>
#include <cstdint>

#define S8     8
#define TENC   12
#define HDIM   256
#define FDIM   316
#define BATCH  1024
#define LDEC   48
#define DBT    32
#define HSP    260          // padded hs row stride (floats): mult of 4, %32==4
#define SCALE_ATTN 0.0625f  // 1/sqrt(256)

__device__ __forceinline__ float sigf(float x) { return 1.0f / (1.0f + expf(-x)); }

__device__ __forceinline__ unsigned short f2bf(float f) {
  unsigned u = __builtin_bit_cast(unsigned, f);
  unsigned r = (u + 0x7fffu + ((u >> 16) & 1u)) >> 16;   // RNE
  return (unsigned short)r;
}
__device__ __forceinline__ float bflo(unsigned u) {
  return __builtin_bit_cast(float, u << 16);
}
__device__ __forceinline__ float bfhi(unsigned u) {
  return __builtin_bit_cast(float, u & 0xffff0000u);
}

#define FMA4(A, xk, W4) \
  A[0] = fmaf(xk, W4.x, A[0]); A[1] = fmaf(xk, W4.y, A[1]); \
  A[2] = fmaf(xk, W4.z, A[2]); A[3] = fmaf(xk, W4.w, A[3]);

// ---------------- transpose: in [S][R][C] -> out [S][C][R] ----------------
__global__ __launch_bounds__(256) void transpose_k(const float* __restrict__ in,
                                                   float* __restrict__ out,
                                                   int R, int C) {
  __shared__ float tile[32][33];
  const int s = blockIdx.z;
  const size_t base = (size_t)s * R * C;
  const int r0 = blockIdx.y * 32, c0 = blockIdx.x * 32;
  const int tx = threadIdx.x & 31, ty = threadIdx.x >> 5;
  for (int i = ty; i < 32; i += 8) {
    int r = r0 + i, c = c0 + tx;
    if (r < R && c < C) tile[i][tx] = in[base + (size_t)r * C + c];
  }
  __syncthreads();
  for (int i = ty; i < 32; i += 8) {
    int c = c0 + i, r = r0 + tx;
    if (c < C && r < R) out[base + (size_t)c * R + r] = tile[tx][i];
  }
}

// ---- repack: WT [S][K][1024] -> Wp [S][K][256] float4 {jj, 256+jj, 512+jj, 768+jj} ----
__global__ __launch_bounds__(256) void repack4(const float* __restrict__ in,
                                               float4* __restrict__ out, int K) {
  const int s = blockIdx.y, k = blockIdx.x, jj = threadIdx.x;
  const float* row = in + ((size_t)s * K + k) * 1024;
  out[((size_t)s * K + k) * 256 + jj] =
      make_float4(row[jj], row[jj + 256], row[jj + 512], row[jj + 768]);
}

// ---- fold A = Wq^T Wk and Mv = Wo Wv, stored AMv[s][k][jj] = {A[jj][k], Mv[jj][k]} ----
__global__ __launch_bounds__(256) void fold_amv(const float* __restrict__ Win,
                                                const float* __restrict__ Wout,
                                                float2* __restrict__ AMv) {
  __shared__ float wks[256][8], wvs[256][8];
  const int s = blockIdx.y, k0 = blockIdx.x * 8, jj = threadIdx.x;
  for (int i = jj; i < 2048; i += 256) {
    int e = i >> 3, kk = i & 7;
    wks[e][kk] = Win[((size_t)s * 768 + 256 + e) * 256 + k0 + kk];
    wvs[e][kk] = Win[((size_t)s * 768 + 512 + e) * 256 + k0 + kk];
  }
  __syncthreads();
  float a[8] = {}, m[8] = {};
  const float* wq = Win + (size_t)s * 768 * 256;            // Wq[e][jj] at e*256+jj
  const float* wo = Wout + ((size_t)s * 256 + jj) * 256;    // Wo[jj][e]
  for (int e = 0; e < 256; ++e) {
    const float q = wq[(size_t)e * 256 + jj], o = wo[e];
#pragma unroll
    for (int kk = 0; kk < 8; ++kk) {
      a[kk] = fmaf(q, wks[e][kk], a[kk]);
      m[kk] = fmaf(o, wvs[e][kk], m[kk]);
    }
  }
  for (int kk = 0; kk < 8; ++kk)
    AMv[((size_t)s * 256 + k0 + kk) * 256 + jj] = make_float2(a[kk], m[kk]);
}

// ---- fold vectors: kbv = Wk^T bq ; cbias = Wo bv + b_out ----
__global__ __launch_bounds__(256) void fold_vec2(const float* __restrict__ Win,
                                                 const float* __restrict__ bin,
                                                 const float* __restrict__ Wout,
                                                 const float* __restrict__ bout,
                                                 float* __restrict__ kbv,
                                                 float* __restrict__ cbias) {
  const int s = blockIdx.x, t = threadIdx.x;
  const float* bq = bin + s * 768;
  const float* bv = bin + s * 768 + 512;
  float a0 = 0.f, a1 = 0.f;
  for (int e = 0; e < 256; ++e) {
    a0 = fmaf(Win[((size_t)s * 768 + 256 + e) * 256 + t], bq[e], a0);
    a1 = fmaf(Wout[((size_t)s * 256 + t) * 256 + e], bv[e], a1);
  }
  kbv[s * 256 + t] = a0;
  cbias[s * 256 + t] = a1 + bout[s * 256 + t];
}

__global__ void fold_bias(const float* __restrict__ a, const float* __restrict__ b,
                          float* __restrict__ o, int n) {
  int i = blockIdx.x * 256 + threadIdx.x;
  if (i < n) o[i] = a[i] + b[i];
}

// ---- decoder teacher-forced inputs ----
__global__ void build_decin(const float* __restrict__ x, const float* __restrict__ tgt,
                            float* __restrict__ dec_in) {
  int idx = blockIdx.x * 256 + threadIdx.x;
  if (idx >= LDEC * BATCH) return;
  int l = idx >> 10, b = idx & 1023;
  dec_in[idx] = (l == 0) ? x[(size_t)b * 96 * FDIM + 95 * FDIM]
                         : tgt[(size_t)b * LDEC + (l - 1)];
}

// =============== THE persistent fused encoder+decoder kernel ===============
// grid (32, 8) x 512 threads. Thread (jj = tid>>1, half = tid&1) owns gate
// columns {c*256+jj} for 16 batch rows; c-state lives in VGPRs for the whole
// 60-step recurrence; h lives in LDS. Each wave reads disjoint weight columns
// -> weight traffic is exactly 1 MB/block/step, coalesced packed float4.
__global__ __launch_bounds__(512, 2) void enc_dec(
    const float* __restrict__ x,
    const float4* __restrict__ Wpx,   // [S][316][256] {i,f,g,o}
    const float4* __restrict__ Wpeh,  // [S][256][256]
    const float4* __restrict__ Wpdh,  // [S][256][256]
    const float* __restrict__ be,     // [S][1024] (b_ih_e + b_hh_e)
    const float* __restrict__ bd,     // [S][1024]
    const float* __restrict__ wihd,   // [S][1024]
    const float2* __restrict__ AMv,   // [S][256][256] {A, Mv}
    const float* __restrict__ kbv,    // [S][256]
    const float* __restrict__ cbias,  // [S][256]
    const float* __restrict__ Wfo,    // [S][512]
    const float* __restrict__ bfo,    // [S]
    const float* __restrict__ decin,  // [L][B]
    unsigned short* __restrict__ kp,  // [T][S][B][256] bf16
    unsigned short* __restrict__ vp,  // [T][S][B][256] bf16
    float* __restrict__ douts)        // [L][S][B]
{
  __shared__ float hs[DBT][HSP];
  __shared__ float sc[DBT][12];
  __shared__ float red[DBT][16];
  __shared__ float dstage[LDEC][DBT];
  __shared__ float kbs[TENC][DBT];

  const int s = blockIdx.y, b0 = blockIdx.x * DBT;
  const int tid = threadIdx.x;
  const int jj = tid >> 1, half = tid & 1, rb = half * 16;

  for (int i = tid; i < DBT * HSP; i += 512) ((float*)hs)[i] = 0.f;

  float creg[16];
#pragma unroll
  for (int i = 0; i < 16; ++i) creg[i] = 0.f;

  float be4[4], bd4[4], wd4[4];
#pragma unroll
  for (int c = 0; c < 4; ++c) {
    be4[c] = be[s * 1024 + c * 256 + jj];
    bd4[c] = bd[s * 1024 + c * 256 + jj];
    wd4[c] = wihd[s * 1024 + c * 256 + jj];
  }
  for (int i = tid; i < LDEC * DBT; i += 512)
    dstage[i >> 5][i & 31] = decin[(size_t)(i >> 5) * BATCH + b0 + (i & 31)];
  __syncthreads();

  const float4* wpx  = Wpx + (size_t)s * FDIM * 256;
  const float4* wpeh = Wpeh + (size_t)s * 256 * 256;
  const float2* amv  = AMv + (size_t)s * 256 * 256;
  const float* kv    = kbv + s * 256;

  // ===================== encoder: 12 steps =====================
  for (int t = 0; t < TENC; ++t) {
    float acc[16][4];
#pragma unroll
    for (int i = 0; i < 16; ++i)
#pragma unroll
      for (int c = 0; c < 4; ++c) acc[i][c] = 0.f;

    // x part (K=316): x rows read directly (L1-broadcast, 2 addrs/wave)
    const size_t xrow = (size_t)(s * TENC + t) * FDIM;
    for (int k = 0; k < FDIM; k += 4) {
      const float4 w0 = wpx[(k + 0) * 256 + jj];
      const float4 w1 = wpx[(k + 1) * 256 + jj];
      const float4 w2 = wpx[(k + 2) * 256 + jj];
      const float4 w3 = wpx[(k + 3) * 256 + jj];
#pragma unroll
      for (int bb = 0; bb < 16; ++bb) {
        const float4 xv = *(const float4*)(x + (size_t)(b0 + rb + bb) * 96 * FDIM + xrow + k);
        FMA4(acc[bb], xv.x, w0); FMA4(acc[bb], xv.y, w1);
        FMA4(acc[bb], xv.z, w2); FMA4(acc[bb], xv.w, w3);
      }
    }
    // h part (K=256)
    for (int k = 0; k < 256; k += 4) {
      const float4 w0 = wpeh[(k + 0) * 256 + jj];
      const float4 w1 = wpeh[(k + 1) * 256 + jj];
      const float4 w2 = wpeh[(k + 2) * 256 + jj];
      const float4 w3 = wpeh[(k + 3) * 256 + jj];
#pragma unroll
      for (int bb = 0; bb < 16; ++bb) {
        const float4 h4 = *(const float4*)(&hs[rb + bb][k]);
        FMA4(acc[bb], h4.x, w0); FMA4(acc[bb], h4.y, w1);
        FMA4(acc[bb], h4.z, w2); FMA4(acc[bb], h4.w, w3);
      }
    }
    // pointwise LSTM (c stays in VGPRs)
    float hv[16];
#pragma unroll
    for (int bb = 0; bb < 16; ++bb) {
      const float gi = sigf(acc[bb][0] + be4[0]);
      const float gf = sigf(acc[bb][1] + be4[1]);
      const float gg = tanhf(acc[bb][2] + be4[2]);
      const float go = sigf(acc[bb][3] + be4[3]);
      const float cn = fmaf(gf, creg[bb], gi * gg);
      creg[bb] = cn;
      hv[bb] = go * tanhf(cn);
    }
    __syncthreads();                       // all reads of old hs done
#pragma unroll
    for (int bb = 0; bb < 16; ++bb) hs[rb + bb][jj] = hv[bb];
    __syncthreads();

    // kp/vp projections: kp[b][jj] = sum_k A[jj][k] h[b][k] (fused float2 weights)
    float ka[16], va[16];
#pragma unroll
    for (int i = 0; i < 16; ++i) { ka[i] = 0.f; va[i] = 0.f; }
    for (int k = 0; k < 256; k += 4) {
      const float2 a0 = amv[(k + 0) * 256 + jj];
      const float2 a1 = amv[(k + 1) * 256 + jj];
      const float2 a2 = amv[(k + 2) * 256 + jj];
      const float2 a3 = amv[(k + 3) * 256 + jj];
#pragma unroll
      for (int bb = 0; bb < 16; ++bb) {
        const float4 h4 = *(const float4*)(&hs[rb + bb][k]);
        ka[bb] = fmaf(h4.x, a0.x, ka[bb]); va[bb] = fmaf(h4.x, a0.y, va[bb]);
        ka[bb] = fmaf(h4.y, a1.x, ka[bb]); va[bb] = fmaf(h4.y, a1.y, va[bb]);
        ka[bb] = fmaf(h4.z, a2.x, ka[bb]); va[bb] = fmaf(h4.z, a2.y, va[bb]);
        ka[bb] = fmaf(h4.w, a3.x, ka[bb]); va[bb] = fmaf(h4.w, a3.y, va[bb]);
      }
    }
    {
      unsigned short* kpw = kp + (((size_t)t * S8 + s) * BATCH + b0) * HDIM;
      unsigned short* vpw = vp + (((size_t)t * S8 + s) * BATCH + b0) * HDIM;
#pragma unroll
      for (int bb = 0; bb < 16; ++bb) {
        kpw[(size_t)(rb + bb) * HDIM + jj] = f2bf(ka[bb]);
        vpw[(size_t)(rb + bb) * HDIM + jj] = f2bf(va[bb]);
      }
    }
    // kb = kbv . h_new -> kbs LDS (never leaves the block)
    {
      const int bbk = tid >> 4, p = tid & 15;
      float a = 0.f;
#pragma unroll
      for (int q = 0; q < 16; ++q) a = fmaf(kv[p * 16 + q], hs[bbk][p * 16 + q], a);
      red[bbk][p] = a;
    }
    __syncthreads();
    if (tid < DBT) {
      float a = 0.f;
#pragma unroll
      for (int p = 0; p < 16; ++p) a += red[tid][p];
      kbs[t][tid] = a;
    }
  }

  // ===================== decoder: 48 steps =====================
  const float4* wpdh = Wpdh + (size_t)s * 256 * 256;
  const float* wfo = Wfo + s * 512;
  const float* cbs = cbias + s * 256;
  const float bfos = bfo[s];
  __syncthreads();

  for (int l = 0; l < LDEC; ++l) {
    float acc[16][4];
#pragma unroll
    for (int i = 0; i < 16; ++i)
#pragma unroll
      for (int c = 0; c < 4; ++c) acc[i][c] = 0.f;

    for (int k = 0; k < 256; k += 4) {
      const float4 w0 = wpdh[(k + 0) * 256 + jj];
      const float4 w1 = wpdh[(k + 1) * 256 + jj];
      const float4 w2 = wpdh[(k + 2) * 256 + jj];
      const float4 w3 = wpdh[(k + 3) * 256 + jj];
#pragma unroll
      for (int bb = 0; bb < 16; ++bb) {
        const float4 h4 = *(const float4*)(&hs[rb + bb][k]);
        FMA4(acc[bb], h4.x, w0); FMA4(acc[bb], h4.y, w1);
        FMA4(acc[bb], h4.z, w2); FMA4(acc[bb], h4.w, w3);
      }
    }
    float hv[16];
#pragma unroll
    for (int bb = 0; bb < 16; ++bb) {
      const float it = dstage[l][rb + bb];
      const float gi = sigf(fmaf(it, wd4[0], acc[bb][0] + bd4[0]));
      const float gf = sigf(fmaf(it, wd4[1], acc[bb][1] + bd4[1]));
      const float gg = tanhf(fmaf(it, wd4[2], acc[bb][2] + bd4[2]));
      const float go = sigf(fmaf(it, wd4[3], acc[bb][3] + bd4[3]));
      const float cn = fmaf(gf, creg[bb], gi * gg);
      creg[bb] = cn;
      hv[bb] = go * tanhf(cn);
    }
    __syncthreads();
#pragma unroll
    for (int bb = 0; bb < 16; ++bb) hs[rb + bb][jj] = hv[bb];
    __syncthreads();

    // scores (32 b x 12 t), bf16 kp against hs
    {
      const int bbs = tid & 31, tts = tid >> 5;
      if (tts < TENC) {
        const uint4* kpr = (const uint4*)(kp + (((size_t)tts * S8 + s) * BATCH + b0 + bbs) * HDIM);
        float a = 0.f;
#pragma unroll 4
        for (int k2 = 0; k2 < 32; ++k2) {
          const uint4 q = kpr[k2];
          const float* hh = &hs[bbs][k2 * 8];
          a = fmaf(bflo(q.x), hh[0], a); a = fmaf(bfhi(q.x), hh[1], a);
          a = fmaf(bflo(q.y), hh[2], a); a = fmaf(bfhi(q.y), hh[3], a);
          a = fmaf(bflo(q.z), hh[4], a); a = fmaf(bfhi(q.z), hh[5], a);
          a = fmaf(bflo(q.w), hh[6], a); a = fmaf(bfhi(q.w), hh[7], a);
        }
        sc[bbs][tts] = (a + kbs[tts][bbs]) * SCALE_ATTN;
      }
    }
    __syncthreads();
    if (tid < DBT) {
      float m = sc[tid][0];
#pragma unroll
      for (int t2 = 1; t2 < TENC; ++t2) m = fmaxf(m, sc[tid][t2]);
      float e[TENC], sum = 0.f;
#pragma unroll
      for (int t2 = 0; t2 < TENC; ++t2) { e[t2] = expf(sc[tid][t2] - m); sum += e[t2]; }
      const float inv = 1.0f / sum;
#pragma unroll
      for (int t2 = 0; t2 < TENC; ++t2) sc[tid][t2] = e[t2] * inv;
    }
    __syncthreads();

    // ctx (bf16 vp) + out_fc: (b 32) x (p 16), 16 dims each
    {
      const int bbc = tid >> 4, p = tid & 15, e0 = p * 16;
      float ctx[16];
#pragma unroll
      for (int ei = 0; ei < 16; ++ei) ctx[ei] = cbs[e0 + ei];
      for (int tt = 0; tt < TENC; ++tt) {
        const float a = sc[bbc][tt];
        const uint4* vpr = (const uint4*)(vp + (((size_t)tt * S8 + s) * BATCH + b0 + bbc) * HDIM + e0);
#pragma unroll
        for (int hf = 0; hf < 2; ++hf) {
          const uint4 q = vpr[hf];
          const int e = hf * 8;
          ctx[e]     = fmaf(a, bflo(q.x), ctx[e]);
          ctx[e + 1] = fmaf(a, bfhi(q.x), ctx[e + 1]);
          ctx[e + 2] = fmaf(a, bflo(q.y), ctx[e + 2]);
          ctx[e + 3] = fmaf(a, bfhi(q.y), ctx[e + 3]);
          ctx[e + 4] = fmaf(a, bflo(q.z), ctx[e + 4]);
          ctx[e + 5] = fmaf(a, bfhi(q.z), ctx[e + 5]);
          ctx[e + 6] = fmaf(a, bflo(q.w), ctx[e + 6]);
          ctx[e + 7] = fmaf(a, bfhi(q.w), ctx[e + 7]);
        }
      }
      float part = 0.f;
#pragma unroll
      for (int ei = 0; ei < 16; ++ei) part = fmaf(ctx[ei], wfo[256 + e0 + ei], part);
#pragma unroll
      for (int ki = 0; ki < 16; ++ki) part = fmaf(hs[bbc][e0 + ki], wfo[e0 + ki], part);
      red[bbc][p] = part;
    }
    __syncthreads();
    if (tid < DBT) {
      float a = 0.f;
#pragma unroll
      for (int p = 0; p < 16; ++p) a += red[tid][p];
      douts[((size_t)l * S8 + s) * BATCH + b0 + tid] = a + bfos;
    }
  }
}

// ---------------- final fc over streams ----------------
__global__ void final_fc(const float* __restrict__ douts, const float* __restrict__ Wfc,
                         const float* __restrict__ bfc, float* __restrict__ out) {
  int idx = blockIdx.x * 256 + threadIdx.x;
  if (idx >= BATCH * LDEC) return;
  int b = idx / LDEC, l = idx - b * LDEC;
  float a = bfc[0];
#pragma unroll
  for (int s = 0; s < S8; ++s)
    a = fmaf(douts[((size_t)l * S8 + s) * BATCH + b], Wfc[s], a);
  out[idx] = a;
}

extern "C" void kernel_launch(void* const* d_in, const int* in_sizes, int n_in,
                              void* d_out, int out_size, void* d_ws, size_t ws_size,
                              hipStream_t stream) {
  const float* x          = (const float*)d_in[0];
  const float* tgt        = (const float*)d_in[1];
  const float* W_ih_e     = (const float*)d_in[2];
  const float* W_hh_e     = (const float*)d_in[3];
  const float* b_ih_e     = (const float*)d_in[4];
  const float* b_hh_e     = (const float*)d_in[5];
  const float* W_ih_d     = (const float*)d_in[6];
  const float* W_hh_d     = (const float*)d_in[7];
  const float* b_ih_d     = (const float*)d_in[8];
  const float* b_hh_d     = (const float*)d_in[9];
  const float* W_in_attn  = (const float*)d_in[10];
  const float* b_in_attn  = (const float*)d_in[11];
  const float* W_out_attn = (const float*)d_in[12];
  const float* b_out_attn = (const float*)d_in[13];
  const float* W_fcout    = (const float*)d_in[14];
  const float* b_fcout    = (const float*)d_in[15];
  const float* W_fc       = (const float*)d_in[16];
  const float* b_fc       = (const float*)d_in[17];

  char* wsb = (char*)d_ws;
  size_t off = 0;
  auto alloc = [&](size_t bytes) {
    void* p = wsb + off; off += (bytes + 255) & ~(size_t)255; return p;
  };
  unsigned short* kp = (unsigned short*)alloc((size_t)TENC * S8 * BATCH * HDIM * 2);
  unsigned short* vp = (unsigned short*)alloc((size_t)TENC * S8 * BATCH * HDIM * 2);
  float*  douts = (float*)alloc((size_t)LDEC * S8 * BATCH * 4);
  float*  decin = (float*)alloc((size_t)LDEC * BATCH * 4);
  float*  WtX   = (float*)alloc((size_t)S8 * FDIM * 1024 * 4);
  float*  WtHe  = (float*)alloc((size_t)S8 * HDIM * 1024 * 4);
  float*  WtHd  = (float*)alloc((size_t)S8 * HDIM * 1024 * 4);
  float4* Wpx   = (float4*)alloc((size_t)S8 * FDIM * 256 * 16);
  float4* Wpeh  = (float4*)alloc((size_t)S8 * HDIM * 256 * 16);
  float4* Wpdh  = (float4*)alloc((size_t)S8 * HDIM * 256 * 16);
  float2* AMv   = (float2*)alloc((size_t)S8 * HDIM * HDIM * 8);
  float*  kbv   = (float*)alloc((size_t)S8 * HDIM * 4);
  float*  cbias = (float*)alloc((size_t)S8 * HDIM * 4);
  float*  beF   = (float*)alloc((size_t)S8 * 1024 * 4);
  float*  bdF   = (float*)alloc((size_t)S8 * 1024 * 4);
  if (off > ws_size) {
    fprintf(stderr, "kernel_launch: ws too small: need %zu bytes, have %zu\n", off, ws_size);
    return;
  }

  // one-time weight preparation
  transpose_k<<<dim3(10, 32, S8), 256, 0, stream>>>(W_ih_e, WtX, 1024, FDIM);
  transpose_k<<<dim3(8, 32, S8), 256, 0, stream>>>(W_hh_e, WtHe, 1024, HDIM);
  transpose_k<<<dim3(8, 32, S8), 256, 0, stream>>>(W_hh_d, WtHd, 1024, HDIM);
  repack4<<<dim3(FDIM, S8), 256, 0, stream>>>(WtX, Wpx, FDIM);
  repack4<<<dim3(HDIM, S8), 256, 0, stream>>>(WtHe, Wpeh, HDIM);
  repack4<<<dim3(HDIM, S8), 256, 0, stream>>>(WtHd, Wpdh, HDIM);
  fold_amv<<<dim3(32, S8), 256, 0, stream>>>(W_in_attn, W_out_attn, AMv);
  fold_vec2<<<S8, 256, 0, stream>>>(W_in_attn, b_in_attn, W_out_attn, b_out_attn, kbv, cbias);
  fold_bias<<<(S8 * 1024 + 255) / 256, 256, 0, stream>>>(b_ih_e, b_hh_e, beF, S8 * 1024);
  fold_bias<<<(S8 * 1024 + 255) / 256, 256, 0, stream>>>(b_ih_d, b_hh_d, bdF, S8 * 1024);
  build_decin<<<(LDEC * BATCH + 255) / 256, 256, 0, stream>>>(x, tgt, decin);

  // the whole recurrent network in one launch
  enc_dec<<<dim3(BATCH / DBT, S8), 512, 0, stream>>>(
      x, Wpx, Wpeh, Wpdh, beF, bdF, W_ih_d, AMv, kbv, cbias,
      W_fcout, b_fcout, decin, kp, vp, douts);

  final_fc<<<(BATCH * LDEC + 255) / 256, 256, 0, stream>>>(douts, W_fc, b_fc, (float*)d_out);
}

// Round 5
// 6389.756 us; speedup vs baseline: 1.9578x; 1.0207x over previous
//
#include <hip/hip_runtime.h>
#include <cstdio>
#include <cstdint>

#define S8     8
#define TENC   12
#define HDIM   256
#define FDIM   316
#define BATCH  1024
#define LDEC   48
#define DBT    32
#define KA     264          // hA row stride in shorts (16B-aligned rows)
#define SCALE_ATTN 0.0625f  // 1/sqrt(256)

typedef short bf16x8 __attribute__((ext_vector_type(8)));
typedef float f32x4  __attribute__((ext_vector_type(4)));

__device__ __forceinline__ float sigf(float x) { return 1.0f / (1.0f + expf(-x)); }

__device__ __forceinline__ unsigned short f2bf(float f) {
  unsigned u = __builtin_bit_cast(unsigned, f);
  unsigned r = (u + 0x7fffu + ((u >> 16) & 1u)) >> 16;   // RNE
  return (unsigned short)r;
}
__device__ __forceinline__ float bflo(unsigned u) {
  return __builtin_bit_cast(float, u << 16);
}
__device__ __forceinline__ float bfhi(unsigned u) {
  return __builtin_bit_cast(float, u & 0xffff0000u);
}

#define MFMA(acc, a, b) acc = __builtin_amdgcn_mfma_f32_16x16x32_bf16(a, b, acc, 0, 0, 0)

// unpack 8 bf16-pairs (hi uint4 + lo uint4) -> 8 floats (hi+lo)
#define UNP8(dst, off, qh, ql) \
  dst[off+0] = bflo(qh.x)+bflo(ql.x); dst[off+1] = bfhi(qh.x)+bfhi(ql.x); \
  dst[off+2] = bflo(qh.y)+bflo(ql.y); dst[off+3] = bfhi(qh.y)+bfhi(ql.y); \
  dst[off+4] = bflo(qh.z)+bflo(ql.z); dst[off+5] = bfhi(qh.z)+bfhi(ql.z); \
  dst[off+6] = bflo(qh.w)+bflo(ql.w); dst[off+7] = bfhi(qh.w)+bfhi(ql.w);

#define DOT8(a, q, hp) \
  a = fmaf(bflo(q.x), hp[0], a); a = fmaf(bfhi(q.x), hp[1], a); \
  a = fmaf(bflo(q.y), hp[2], a); a = fmaf(bfhi(q.y), hp[3], a); \
  a = fmaf(bflo(q.z), hp[4], a); a = fmaf(bfhi(q.z), hp[5], a); \
  a = fmaf(bflo(q.w), hp[6], a); a = fmaf(bfhi(q.w), hp[7], a);

// ---------------- transpose: in [S][R][C] -> out [S][C][R] ----------------
__global__ __launch_bounds__(256) void transpose_k(const float* __restrict__ in,
                                                   float* __restrict__ out,
                                                   int R, int C) {
  __shared__ float tile[32][33];
  const int s = blockIdx.z;
  const size_t base = (size_t)s * R * C;
  const int r0 = blockIdx.y * 32, c0 = blockIdx.x * 32;
  const int tx = threadIdx.x & 31, ty = threadIdx.x >> 5;
  for (int i = ty; i < 32; i += 8) {
    int r = r0 + i, c = c0 + tx;
    if (r < R && c < C) tile[i][tx] = in[base + (size_t)r * C + c];
  }
  __syncthreads();
  for (int i = ty; i < 32; i += 8) {
    int c = c0 + i, r = r0 + tx;
    if (c < C && r < R) out[base + (size_t)c * R + r] = tile[tx][i];
  }
}

// ---- fold GEMM: out[s][r][col] = sum_e A[s][e][r] * B[s][e][col], 256x256, K=256 ----
__global__ __launch_bounds__(256) void fold_gemm(const float* __restrict__ A, size_t sA,
                                                 const float* __restrict__ Bm, size_t sB,
                                                 float* __restrict__ out, size_t sO) {
  const int s = blockIdx.y, r0 = blockIdx.x * 32, col = threadIdx.x;
  A += (size_t)s * sA; Bm += (size_t)s * sB; out += (size_t)s * sO;
  float acc[32] = {};
  for (int e = 0; e < HDIM; ++e) {
    const float bvv = Bm[(size_t)e * HDIM + col];
#pragma unroll
    for (int r = 0; r < 32; ++r) acc[r] = fmaf(A[(size_t)e * HDIM + r0 + r], bvv, acc[r]);
  }
  for (int r = 0; r < 32; ++r) out[(size_t)(r0 + r) * HDIM + col] = acc[r];
}

// ---- pack gate weights [S][1024][Ksrc] into B-fragment layout, hi+lo bf16 ----
// out idx: (((s*ksT + ks)*64 + nt)*64 + lane), lane holds B[k=ks*32+quad*8+j][n=nt*16+l15]
__global__ __launch_bounds__(64) void pack_hl(const float* __restrict__ src, int Ksrc, int ksT,
                                              bf16x8* __restrict__ outhi,
                                              bf16x8* __restrict__ outlo) {
  const int s = blockIdx.z, ks = blockIdx.y, nt = blockIdx.x;
  const int lane = threadIdx.x, l15 = lane & 15, quad = lane >> 4;
  const int n = nt * 16 + l15, kb = ks * 32 + quad * 8;
  const float* row = src + ((size_t)s * 1024 + n) * Ksrc;
  union { bf16x8 v; unsigned short e[8]; } h, l;
#pragma unroll
  for (int j = 0; j < 8; ++j) {
    const int k = kb + j;
    const float v = (k < Ksrc) ? row[k] : 0.f;
    const unsigned short hi = f2bf(v);
    h.e[j] = hi;
    l.e[j] = f2bf(v - bflo(hi));
  }
  const size_t idx = (((size_t)s * ksT + ks) * 64 + nt) * 64 + lane;
  outhi[idx] = h.v;
  outlo[idx] = l.v;
}

// ---- pack attention fold matrices [S][256][256] into B-frag (single bf16), NTtot=32 ----
__global__ __launch_bounds__(64) void pack_s(const float* __restrict__ src, int ntOff,
                                             bf16x8* __restrict__ out) {
  const int s = blockIdx.z, ks = blockIdx.y, nt = blockIdx.x;
  const int lane = threadIdx.x, l15 = lane & 15, quad = lane >> 4;
  const int n = nt * 16 + l15, kb = ks * 32 + quad * 8;
  const float* row = src + ((size_t)s * 256 + n) * 256;
  union { bf16x8 v; unsigned short e[8]; } h;
#pragma unroll
  for (int j = 0; j < 8; ++j) h.e[j] = f2bf(row[kb + j]);
  out[(((size_t)s * 8 + ks) * 32 + ntOff + nt) * 64 + lane] = h.v;
}

// ---- fold vectors: kbv = Wk^T bq ; cbias = Wo bv + b_out ----
__global__ __launch_bounds__(256) void fold_vec2(const float* __restrict__ Win,
                                                 const float* __restrict__ bin,
                                                 const float* __restrict__ Wout,
                                                 const float* __restrict__ bout,
                                                 float* __restrict__ kbv,
                                                 float* __restrict__ cbias) {
  const int s = blockIdx.x, t = threadIdx.x;
  const float* bq = bin + s * 768;
  const float* bv = bin + s * 768 + 512;
  float a0 = 0.f, a1 = 0.f;
  for (int e = 0; e < 256; ++e) {
    a0 = fmaf(Win[((size_t)s * 768 + 256 + e) * 256 + t], bq[e], a0);
    a1 = fmaf(Wout[((size_t)s * 256 + t) * 256 + e], bv[e], a1);
  }
  kbv[s * 256 + t] = a0;
  cbias[s * 256 + t] = a1 + bout[s * 256 + t];
}

__global__ void fold_bias(const float* __restrict__ a, const float* __restrict__ b,
                          float* __restrict__ o, int n) {
  int i = blockIdx.x * 256 + threadIdx.x;
  if (i < n) o[i] = a[i] + b[i];
}

__global__ void build_decin(const float* __restrict__ x, const float* __restrict__ tgt,
                            float* __restrict__ dec_in) {
  int idx = blockIdx.x * 256 + threadIdx.x;
  if (idx >= LDEC * BATCH) return;
  int l = idx >> 10, b = idx & 1023;
  dec_in[idx] = (l == 0) ? x[(size_t)b * 96 * FDIM + 95 * FDIM]
                         : tgt[(size_t)b * LDEC + (l - 1)];
}

// =============== persistent MFMA encoder+decoder ===============
// grid 256 x 512thr. s = bid&7 (XCD weight locality), 32 batch rows/block.
// Wave w owns gate cols [32w,32w+32). MFMA 16x16x32 bf16 with hi/lo split.
__global__ __launch_bounds__(512, 2) void enc_dec(
    const float* __restrict__ x,
    const bf16x8* __restrict__ WxH, const bf16x8* __restrict__ WxL,
    const bf16x8* __restrict__ WeH, const bf16x8* __restrict__ WeL,
    const bf16x8* __restrict__ WdH, const bf16x8* __restrict__ WdL,
    const bf16x8* __restrict__ AMvF,
    const float* __restrict__ be, const float* __restrict__ bd,
    const float* __restrict__ wihd,
    const float* __restrict__ kbv, const float* __restrict__ cbias,
    const float* __restrict__ Wfo, const float* __restrict__ bfo,
    const float* __restrict__ decin,
    unsigned short* __restrict__ kp, unsigned short* __restrict__ vp,
    float* __restrict__ douts)
{
  __shared__ unsigned short hAhi[DBT * KA];
  __shared__ unsigned short hAlo[DBT * KA];
  __shared__ float redS[DBT][TENC][9];
  __shared__ float sc[DBT][TENC];
  __shared__ float red[DBT][16];
  __shared__ float kbs[TENC][DBT];

  const int bid = blockIdx.x;
  const int s = bid & 7, b0 = (bid >> 3) * DBT;
  const int tid = threadIdx.x;
  const int w = tid >> 6, lane = tid & 63, l15 = lane & 15, quad = lane >> 4;

  for (int i = tid; i < DBT * KA; i += 512) { hAhi[i] = 0; hAlo[i] = 0; }

  // per-lane constants (cols J = c*256 + 32w + 16st + l15)
  float beV[4][2], bdV[4][2], wdV[4][2];
#pragma unroll
  for (int c = 0; c < 4; ++c)
#pragma unroll
    for (int st = 0; st < 2; ++st) {
      const int J = c * 256 + 32 * w + 16 * st + l15;
      beV[c][st] = be[s * 1024 + J];
      bdV[c][st] = bd[s * 1024 + J];
      wdV[c][st] = wihd[s * 1024 + J];
    }
  float cst[2][2][4];
#pragma unroll
  for (int a = 0; a < 2; ++a)
#pragma unroll
    for (int b = 0; b < 2; ++b)
#pragma unroll
      for (int r = 0; r < 4; ++r) cst[a][b][r] = 0.f;

  const bf16x8* wxh = WxH + (size_t)s * 10 * 64 * 64;
  const bf16x8* wxl = WxL + (size_t)s * 10 * 64 * 64;
  const bf16x8* weh = WeH + (size_t)s * 8 * 64 * 64;
  const bf16x8* wel = WeL + (size_t)s * 8 * 64 * 64;
  const bf16x8* wdh = WdH + (size_t)s * 8 * 64 * 64;
  const bf16x8* wdl = WdL + (size_t)s * 8 * 64 * 64;
  const bf16x8* amv = AMvF + (size_t)s * 8 * 32 * 64;
  const float* kvv = kbv + s * 256;
  const float* cbs = cbias + s * 256;
  const float* wfo = Wfo + s * 512;
  const float bfos = bfo[s];

  __syncthreads();

  // ===================== encoder =====================
  for (int t = 0; t < TENC; ++t) {
    f32x4 acc[2][2][4];
#pragma unroll
    for (int mt = 0; mt < 2; ++mt)
#pragma unroll
      for (int st = 0; st < 2; ++st)
#pragma unroll
        for (int c = 0; c < 4; ++c) acc[mt][st][c] = (f32x4){0.f, 0.f, 0.f, 0.f};

    const size_t xoff = (size_t)(s * TENC + t) * FDIM;
    // x-part: K padded to 320 (10 ksteps), A-frags built in-register from fp32 x
    for (int ks = 0; ks < 10; ++ks) {
      bf16x8 axh[2], axl[2];
#pragma unroll
      for (int mt = 0; mt < 2; ++mt) {
        const float* xr = x + (size_t)(b0 + 16 * mt + l15) * (96 * FDIM) + xoff + ks * 32 + quad * 8;
        const float4 v0 = *(const float4*)xr;
        float4 v1;
        if (ks == 9 && quad == 3) v1 = make_float4(0.f, 0.f, 0.f, 0.f);
        else v1 = *(const float4*)(xr + 4);
        const float vv[8] = {v0.x, v0.y, v0.z, v0.w, v1.x, v1.y, v1.z, v1.w};
        union { bf16x8 v; unsigned short e[8]; } uh, ul;
#pragma unroll
        for (int j = 0; j < 8; ++j) {
          const unsigned short hi = f2bf(vv[j]);
          uh.e[j] = hi;
          ul.e[j] = f2bf(vv[j] - bflo(hi));
        }
        axh[mt] = uh.v; axl[mt] = ul.v;
      }
#pragma unroll
      for (int st = 0; st < 2; ++st)
#pragma unroll
        for (int c = 0; c < 4; ++c) {
          const int nt = c * 16 + 2 * w + st;
          const bf16x8 bh = wxh[(ks * 64 + nt) * 64 + lane];
          const bf16x8 bl = wxl[(ks * 64 + nt) * 64 + lane];
          MFMA(acc[0][st][c], axh[0], bh); MFMA(acc[0][st][c], axh[0], bl); MFMA(acc[0][st][c], axl[0], bh);
          MFMA(acc[1][st][c], axh[1], bh); MFMA(acc[1][st][c], axh[1], bl); MFMA(acc[1][st][c], axl[1], bh);
        }
    }
    // h-part: 8 ksteps, A-frags from LDS
    for (int ks = 0; ks < 8; ++ks) {
      bf16x8 ah[2], al[2];
#pragma unroll
      for (int mt = 0; mt < 2; ++mt) {
        const int ao = (16 * mt + l15) * KA + ks * 32 + quad * 8;
        ah[mt] = *(const bf16x8*)&hAhi[ao];
        al[mt] = *(const bf16x8*)&hAlo[ao];
      }
#pragma unroll
      for (int st = 0; st < 2; ++st)
#pragma unroll
        for (int c = 0; c < 4; ++c) {
          const int nt = c * 16 + 2 * w + st;
          const bf16x8 bh = weh[(ks * 64 + nt) * 64 + lane];
          const bf16x8 bl = wel[(ks * 64 + nt) * 64 + lane];
          MFMA(acc[0][st][c], ah[0], bh); MFMA(acc[0][st][c], ah[0], bl); MFMA(acc[0][st][c], al[0], bh);
          MFMA(acc[1][st][c], ah[1], bh); MFMA(acc[1][st][c], ah[1], bl); MFMA(acc[1][st][c], al[1], bh);
        }
    }
    // pointwise LSTM
    float hv[2][2][4];
#pragma unroll
    for (int mt = 0; mt < 2; ++mt)
#pragma unroll
      for (int st = 0; st < 2; ++st)
#pragma unroll
        for (int reg = 0; reg < 4; ++reg) {
          const float gi = sigf(acc[mt][st][0][reg] + beV[0][st]);
          const float gf = sigf(acc[mt][st][1][reg] + beV[1][st]);
          const float gg = tanhf(acc[mt][st][2][reg] + beV[2][st]);
          const float go = sigf(acc[mt][st][3][reg] + beV[3][st]);
          const float cn = fmaf(gf, cst[mt][st][reg], gi * gg);
          cst[mt][st][reg] = cn;
          hv[mt][st][reg] = go * tanhf(cn);
        }
    __syncthreads();   // all reads of old hA done
#pragma unroll
    for (int mt = 0; mt < 2; ++mt)
#pragma unroll
      for (int st = 0; st < 2; ++st)
#pragma unroll
        for (int reg = 0; reg < 4; ++reg) {
          const int R = 16 * mt + 4 * quad + reg;
          const int J = 32 * w + 16 * st + l15;
          const float v = hv[mt][st][reg];
          const unsigned short hi = f2bf(v);
          hAhi[R * KA + J] = hi;
          hAlo[R * KA + J] = f2bf(v - bflo(hi));
        }
    __syncthreads();

    // kp/vp projection MFMA: A = new h (hi/lo), B = AMvF (single bf16)
    f32x4 ak[2][2][2];
#pragma unroll
    for (int mt = 0; mt < 2; ++mt)
#pragma unroll
      for (int st = 0; st < 2; ++st)
#pragma unroll
        for (int kv = 0; kv < 2; ++kv) ak[mt][st][kv] = (f32x4){0.f, 0.f, 0.f, 0.f};
    for (int ks = 0; ks < 8; ++ks) {
      bf16x8 ah[2], al[2];
#pragma unroll
      for (int mt = 0; mt < 2; ++mt) {
        const int ao = (16 * mt + l15) * KA + ks * 32 + quad * 8;
        ah[mt] = *(const bf16x8*)&hAhi[ao];
        al[mt] = *(const bf16x8*)&hAlo[ao];
      }
#pragma unroll
      for (int st = 0; st < 2; ++st)
#pragma unroll
        for (int kv = 0; kv < 2; ++kv) {
          const int nt = kv * 16 + 2 * w + st;
          const bf16x8 b = amv[(ks * 32 + nt) * 64 + lane];
          MFMA(ak[0][st][kv], ah[0], b); MFMA(ak[0][st][kv], al[0], b);
          MFMA(ak[1][st][kv], ah[1], b); MFMA(ak[1][st][kv], al[1], b);
        }
    }
    {
      unsigned short* kpw = kp + (((size_t)t * S8 + s) * BATCH + b0) * HDIM;
      unsigned short* vpw = vp + (((size_t)t * S8 + s) * BATCH + b0) * HDIM;
#pragma unroll
      for (int mt = 0; mt < 2; ++mt)
#pragma unroll
        for (int st = 0; st < 2; ++st)
#pragma unroll
          for (int reg = 0; reg < 4; ++reg) {
            const int R = 16 * mt + 4 * quad + reg;
            const int J2 = 32 * w + 16 * st + l15;
            kpw[(size_t)R * HDIM + J2] = f2bf(ak[mt][st][0][reg]);
            vpw[(size_t)R * HDIM + J2] = f2bf(ak[mt][st][1][reg]);
          }
    }
    // kb = kbv . h_new
    {
      const int bbk = tid >> 4, p = tid & 15;
      const uint4 qh0 = *(const uint4*)&hAhi[bbk * KA + p * 16];
      const uint4 qh1 = *(const uint4*)&hAhi[bbk * KA + p * 16 + 8];
      const uint4 ql0 = *(const uint4*)&hAlo[bbk * KA + p * 16];
      const uint4 ql1 = *(const uint4*)&hAlo[bbk * KA + p * 16 + 8];
      float hh[16];
      UNP8(hh, 0, qh0, ql0);
      UNP8(hh, 8, qh1, ql1);
      float a = 0.f;
#pragma unroll
      for (int q = 0; q < 16; ++q) a = fmaf(kvv[p * 16 + q], hh[q], a);
      red[bbk][p] = a;
    }
    __syncthreads();
    if (tid < DBT) {
      float a = 0.f;
#pragma unroll
      for (int p = 0; p < 16; ++p) a += red[tid][p];
      kbs[t][tid] = a;
    }
    __syncthreads();
  }

  // ===================== decoder =====================
  for (int l = 0; l < LDEC; ++l) {
    f32x4 acc[2][2][4];
#pragma unroll
    for (int mt = 0; mt < 2; ++mt)
#pragma unroll
      for (int st = 0; st < 2; ++st)
#pragma unroll
        for (int c = 0; c < 4; ++c) acc[mt][st][c] = (f32x4){0.f, 0.f, 0.f, 0.f};

    for (int ks = 0; ks < 8; ++ks) {
      bf16x8 ah[2], al[2];
#pragma unroll
      for (int mt = 0; mt < 2; ++mt) {
        const int ao = (16 * mt + l15) * KA + ks * 32 + quad * 8;
        ah[mt] = *(const bf16x8*)&hAhi[ao];
        al[mt] = *(const bf16x8*)&hAlo[ao];
      }
#pragma unroll
      for (int st = 0; st < 2; ++st)
#pragma unroll
        for (int c = 0; c < 4; ++c) {
          const int nt = c * 16 + 2 * w + st;
          const bf16x8 bh = wdh[(ks * 64 + nt) * 64 + lane];
          const bf16x8 bl = wdl[(ks * 64 + nt) * 64 + lane];
          MFMA(acc[0][st][c], ah[0], bh); MFMA(acc[0][st][c], ah[0], bl); MFMA(acc[0][st][c], al[0], bh);
          MFMA(acc[1][st][c], ah[1], bh); MFMA(acc[1][st][c], ah[1], bl); MFMA(acc[1][st][c], al[1], bh);
        }
    }
    float hv[2][2][4];
#pragma unroll
    for (int mt = 0; mt < 2; ++mt)
#pragma unroll
      for (int reg = 0; reg < 4; ++reg) {
        const int R = 16 * mt + 4 * quad + reg;
        const float it = decin[(size_t)l * BATCH + b0 + R];
#pragma unroll
        for (int st = 0; st < 2; ++st) {
          const float gi = sigf(fmaf(it, wdV[0][st], acc[mt][st][0][reg] + bdV[0][st]));
          const float gf = sigf(fmaf(it, wdV[1][st], acc[mt][st][1][reg] + bdV[1][st]));
          const float gg = tanhf(fmaf(it, wdV[2][st], acc[mt][st][2][reg] + bdV[2][st]));
          const float go = sigf(fmaf(it, wdV[3][st], acc[mt][st][3][reg] + bdV[3][st]));
          const float cn = fmaf(gf, cst[mt][st][reg], gi * gg);
          cst[mt][st][reg] = cn;
          hv[mt][st][reg] = go * tanhf(cn);
        }
      }
    __syncthreads();
#pragma unroll
    for (int mt = 0; mt < 2; ++mt)
#pragma unroll
      for (int st = 0; st < 2; ++st)
#pragma unroll
        for (int reg = 0; reg < 4; ++reg) {
          const int R = 16 * mt + 4 * quad + reg;
          const int J = 32 * w + 16 * st + l15;
          const float v = hv[mt][st][reg];
          const unsigned short hi = f2bf(v);
          hAhi[R * KA + J] = hi;
          hAlo[R * KA + J] = f2bf(v - bflo(hi));
        }
    __syncthreads();

    // scores S1: thread (bbs, p<8): 32-k chunk, each h element read once
    if (tid < 256) {
      const int bbs = tid & 31, p = tid >> 5;
      const int k0 = p * 32;
      float hh[32];
      {
        const uint4* ph = (const uint4*)&hAhi[bbs * KA + k0];
        const uint4* pl = (const uint4*)&hAlo[bbs * KA + k0];
#pragma unroll
        for (int g = 0; g < 4; ++g) {
          const uint4 qh = ph[g], ql = pl[g];
          UNP8(hh, g * 8, qh, ql);
        }
      }
#pragma unroll 2
      for (int tts = 0; tts < TENC; ++tts) {
        const uint4* kq = (const uint4*)(kp + (((size_t)tts * S8 + s) * BATCH + b0 + bbs) * HDIM + k0);
        float a = 0.f;
#pragma unroll
        for (int g = 0; g < 4; ++g) {
          const uint4 q = kq[g];
          const float* hp = &hh[g * 8];
          DOT8(a, q, hp);
        }
        redS[bbs][tts][p] = a;
      }
    }
    __syncthreads();
    if (tid < 384) {
      const int bbs = tid & 31, tts = tid >> 5;
      float a = kbs[tts][bbs];
#pragma unroll
      for (int q = 0; q < 8; ++q) a += redS[bbs][tts][q];
      sc[bbs][tts] = a * SCALE_ATTN;
    }
    __syncthreads();
    if (tid < DBT) {
      float m = sc[tid][0];
#pragma unroll
      for (int t2 = 1; t2 < TENC; ++t2) m = fmaxf(m, sc[tid][t2]);
      float e[TENC], sum = 0.f;
#pragma unroll
      for (int t2 = 0; t2 < TENC; ++t2) { e[t2] = expf(sc[tid][t2] - m); sum += e[t2]; }
      const float inv = 1.0f / sum;
#pragma unroll
      for (int t2 = 0; t2 < TENC; ++t2) sc[tid][t2] = e[t2] * inv;
    }
    __syncthreads();

    // ctx + out_fc
    {
      const int bbc = tid >> 4, p = tid & 15, e0 = p * 16;
      float ctxv[16];
#pragma unroll
      for (int ei = 0; ei < 16; ++ei) ctxv[ei] = cbs[e0 + ei];
      for (int tt = 0; tt < TENC; ++tt) {
        const float a = sc[bbc][tt];
        const uint4* vpr = (const uint4*)(vp + (((size_t)tt * S8 + s) * BATCH + b0 + bbc) * HDIM + e0);
#pragma unroll
        for (int hf = 0; hf < 2; ++hf) {
          const uint4 q = vpr[hf];
          const int e = hf * 8;
          ctxv[e]     = fmaf(a, bflo(q.x), ctxv[e]);
          ctxv[e + 1] = fmaf(a, bfhi(q.x), ctxv[e + 1]);
          ctxv[e + 2] = fmaf(a, bflo(q.y), ctxv[e + 2]);
          ctxv[e + 3] = fmaf(a, bfhi(q.y), ctxv[e + 3]);
          ctxv[e + 4] = fmaf(a, bflo(q.z), ctxv[e + 4]);
          ctxv[e + 5] = fmaf(a, bfhi(q.z), ctxv[e + 5]);
          ctxv[e + 6] = fmaf(a, bflo(q.w), ctxv[e + 6]);
          ctxv[e + 7] = fmaf(a, bfhi(q.w), ctxv[e + 7]);
        }
      }
      float part = 0.f;
#pragma unroll
      for (int ei = 0; ei < 16; ++ei) part = fmaf(ctxv[ei], wfo[256 + e0 + ei], part);
      {
        const uint4 qh0 = *(const uint4*)&hAhi[bbc * KA + e0];
        const uint4 qh1 = *(const uint4*)&hAhi[bbc * KA + e0 + 8];
        const uint4 ql0 = *(const uint4*)&hAlo[bbc * KA + e0];
        const uint4 ql1 = *(const uint4*)&hAlo[bbc * KA + e0 + 8];
        float hh[16];
        UNP8(hh, 0, qh0, ql0);
        UNP8(hh, 8, qh1, ql1);
#pragma unroll
        for (int ki = 0; ki < 16; ++ki) part = fmaf(hh[ki], wfo[e0 + ki], part);
      }
      red[bbc][p] = part;
    }
    __syncthreads();
    if (tid < DBT) {
      float a = 0.f;
#pragma unroll
      for (int p = 0; p < 16; ++p) a += red[tid][p];
      douts[((size_t)l * S8 + s) * BATCH + b0 + tid] = a + bfos;
    }
    __syncthreads();
  }
}

// ---------------- final fc over streams ----------------
__global__ void final_fc(const float* __restrict__ douts, const float* __restrict__ Wfc,
                         const float* __restrict__ bfc, float* __restrict__ out) {
  int idx = blockIdx.x * 256 + threadIdx.x;
  if (idx >= BATCH * LDEC) return;
  int b = idx / LDEC, l = idx - b * LDEC;
  float a = bfc[0];
#pragma unroll
  for (int s = 0; s < S8; ++s)
    a = fmaf(douts[((size_t)l * S8 + s) * BATCH + b], Wfc[s], a);
  out[idx] = a;
}

extern "C" void kernel_launch(void* const* d_in, const int* in_sizes, int n_in,
                              void* d_out, int out_size, void* d_ws, size_t ws_size,
                              hipStream_t stream) {
  const float* x          = (const float*)d_in[0];
  const float* tgt        = (const float*)d_in[1];
  const float* W_ih_e     = (const float*)d_in[2];
  const float* W_hh_e     = (const float*)d_in[3];
  const float* b_ih_e     = (const float*)d_in[4];
  const float* b_hh_e     = (const float*)d_in[5];
  const float* W_ih_d     = (const float*)d_in[6];
  const float* W_hh_d     = (const float*)d_in[7];
  const float* b_ih_d     = (const float*)d_in[8];
  const float* b_hh_d     = (const float*)d_in[9];
  const float* W_in_attn  = (const float*)d_in[10];
  const float* b_in_attn  = (const float*)d_in[11];
  const float* W_out_attn = (const float*)d_in[12];
  const float* b_out_attn = (const float*)d_in[13];
  const float* W_fcout    = (const float*)d_in[14];
  const float* b_fcout    = (const float*)d_in[15];
  const float* W_fc       = (const float*)d_in[16];
  const float* b_fc       = (const float*)d_in[17];

  char* wsb = (char*)d_ws;
  size_t off = 0;
  auto alloc = [&](size_t bytes) {
    void* p = wsb + off; off += (bytes + 255) & ~(size_t)255; return p;
  };
  unsigned short* kp = (unsigned short*)alloc((size_t)TENC * S8 * BATCH * HDIM * 2);
  unsigned short* vp = (unsigned short*)alloc((size_t)TENC * S8 * BATCH * HDIM * 2);
  float*  douts = (float*)alloc((size_t)LDEC * S8 * BATCH * 4);
  float*  decin = (float*)alloc((size_t)LDEC * BATCH * 4);
  float*  Pmat  = (float*)alloc((size_t)S8 * 256 * 256 * 4);
  float*  Mvmat = (float*)alloc((size_t)S8 * 256 * 256 * 4);
  float*  WoT   = (float*)alloc((size_t)S8 * 256 * 256 * 4);
  bf16x8* WxH   = (bf16x8*)alloc((size_t)S8 * 10 * 64 * 64 * 16);
  bf16x8* WxL   = (bf16x8*)alloc((size_t)S8 * 10 * 64 * 64 * 16);
  bf16x8* WeH   = (bf16x8*)alloc((size_t)S8 * 8 * 64 * 64 * 16);
  bf16x8* WeL   = (bf16x8*)alloc((size_t)S8 * 8 * 64 * 64 * 16);
  bf16x8* WdH   = (bf16x8*)alloc((size_t)S8 * 8 * 64 * 64 * 16);
  bf16x8* WdL   = (bf16x8*)alloc((size_t)S8 * 8 * 64 * 64 * 16);
  bf16x8* AMvF  = (bf16x8*)alloc((size_t)S8 * 8 * 32 * 64 * 16);
  float*  kbv   = (float*)alloc((size_t)S8 * 256 * 4);
  float*  cbias = (float*)alloc((size_t)S8 * 256 * 4);
  float*  beF   = (float*)alloc((size_t)S8 * 1024 * 4);
  float*  bdF   = (float*)alloc((size_t)S8 * 1024 * 4);
  if (off > ws_size) {
    fprintf(stderr, "kernel_launch: ws too small: need %zu bytes, have %zu\n", off, ws_size);
    return;
  }

  // ---- one-time weight preparation ----
  transpose_k<<<dim3(8, 8, S8), 256, 0, stream>>>(W_out_attn, WoT, 256, 256);
  // P[n][k] = sum_e Wq[e][n] Wk[e][k]
  fold_gemm<<<dim3(8, S8), 256, 0, stream>>>(W_in_attn, (size_t)768 * 256,
                                             W_in_attn + 256 * 256, (size_t)768 * 256,
                                             Pmat, (size_t)256 * 256);
  // Mv[o][k] = sum_e Wo[o][e] Wv[e][k]
  fold_gemm<<<dim3(8, S8), 256, 0, stream>>>(WoT, (size_t)256 * 256,
                                             W_in_attn + 2 * 256 * 256, (size_t)768 * 256,
                                             Mvmat, (size_t)256 * 256);
  pack_hl<<<dim3(64, 10, S8), 64, 0, stream>>>(W_ih_e, FDIM, 10, WxH, WxL);
  pack_hl<<<dim3(64, 8, S8), 64, 0, stream>>>(W_hh_e, 256, 8, WeH, WeL);
  pack_hl<<<dim3(64, 8, S8), 64, 0, stream>>>(W_hh_d, 256, 8, WdH, WdL);
  pack_s<<<dim3(16, 8, S8), 64, 0, stream>>>(Pmat, 0, AMvF);
  pack_s<<<dim3(16, 8, S8), 64, 0, stream>>>(Mvmat, 16, AMvF);
  fold_vec2<<<S8, 256, 0, stream>>>(W_in_attn, b_in_attn, W_out_attn, b_out_attn, kbv, cbias);
  fold_bias<<<(S8 * 1024 + 255) / 256, 256, 0, stream>>>(b_ih_e, b_hh_e, beF, S8 * 1024);
  fold_bias<<<(S8 * 1024 + 255) / 256, 256, 0, stream>>>(b_ih_d, b_hh_d, bdF, S8 * 1024);
  build_decin<<<(LDEC * BATCH + 255) / 256, 256, 0, stream>>>(x, tgt, decin);

  // the whole recurrent network, MFMA path
  enc_dec<<<256, 512, 0, stream>>>(
      x, WxH, WxL, WeH, WeL, WdH, WdL, AMvF, beF, bdF, W_ih_d,
      kbv, cbias, W_fcout, b_fcout, decin, kp, vp, douts);

  final_fc<<<(BATCH * LDEC + 255) / 256, 256, 0, stream>>>(douts, W_fc, b_fc, (float*)d_out);
}